// Round 1
// baseline (756.394 us; speedup 1.0000x reference)
//
#include <hip/hip_runtime.h>
#include <hip/hip_bf16.h>

// Discriminator pipeline, fp32 throughout.
// Stages: layout_bbox -> conv1(7->32,5x5,s2) -> BN1+leaky -> conv2(32->64,5x5,s2)
//         -> BN2+leaky -> [transpose to (K,M)] -> fc1 (split-K GEMM) -> BN3+leaky
//         -> fc2 -> sigmoid.
// NOTE: conv1_b / conv2_b / fc1_b are mathematically absorbed by the following
// batch-norms (constant per BN channel => cancels in x - mean, var unchanged),
// so they are intentionally not applied.

#define LEAKY(v) ((v) > 0.0f ? (v) : 0.2f * (v))
#define CLIP01(v) fminf(fmaxf((v), 0.0f), 1.0f)

constexpr int HW = 108;     // layout spatial
constexpr int NOBJ = 16;
constexpr int NCLS = 7;
constexpr int K1FEAT = 36864;  // 64*24*24

// ---------------------------------------------------------------- layout_bbox
// grid (108 h, 64 b), block 128 (lane = w). Writes layoutT[b][c][h][w].
__global__ __launch_bounds__(128) void layout_kernel(
    const float* __restrict__ image, float* __restrict__ out) {
  int h = blockIdx.x, b = blockIdx.y;
  __shared__ float sIm[NOBJ * 11];
  int tid = threadIdx.x;
  for (int i = tid; i < NOBJ * 11; i += 128) sIm[i] = image[b * NOBJ * 11 + i];
  __syncthreads();
  int w = tid;
  if (w >= HW) return;
  float best[NCLS];
#pragma unroll
  for (int c = 0; c < NCLS; ++c) best[c] = 0.0f;  // all products >= 0
  float fw = (float)w, fh = (float)h;
  for (int o = 0; o < NOBJ; ++o) {
    const float* p = &sIm[o * 11];
    float xc = p[0] * 108.0f, yc = p[1] * 108.0f;
    float wd = p[2] * 108.0f, hd = p[3] * 108.0f;
    float x1 = xc - 0.5f * wd, x2 = xc + 0.5f * wd;
    float y1 = yc - 0.5f * hd, y2 = yc + 0.5f * hd;
    float x1d = fw - x1, x2d = x2 - fw;
    float y1d = fh - y1, y2d = y2 - fh;
    float yband = CLIP01(y1d) * CLIP01(y2d);
    float xband = CLIP01(x1d) * CLIP01(x2d);
    float x1l = fmaxf(1.0f - fabsf(x1d), 0.0f) * yband;
    float x2l = fmaxf(1.0f - fabsf(x2d), 0.0f) * yband;
    float y1l = fmaxf(1.0f - fabsf(y1d), 0.0f) * xband;
    float y2l = fmaxf(1.0f - fabsf(y2d), 0.0f) * xband;
    float xy = fmaxf(fmaxf(x1l, x2l), fmaxf(y1l, y2l));
#pragma unroll
    for (int c = 0; c < NCLS; ++c) best[c] = fmaxf(best[c], xy * p[4 + c]);
  }
#pragma unroll
  for (int c = 0; c < NCLS; ++c)
    out[((b * NCLS + c) * HW + h) * HW + w] = best[c];
}

// -------------------------------------------------------------------- conv1
// grid (52 h, 64 b), block 128 = (co 0..31) x (wg 0..3, 13 outputs each).
__global__ __launch_bounds__(128) void conv1_kernel(
    const float* __restrict__ lay, const float* __restrict__ w1,
    float* __restrict__ out) {
  int h = blockIdx.x, b = blockIdx.y;
  __shared__ float sIn[7 * 5 * 108];  // [ci][kh][col]
  __shared__ float sW[32 * 175];      // [co][ci*25+kh*5+kw]
  int tid = threadIdx.x;
  for (int i = tid; i < 32 * 175; i += 128) sW[i] = w1[i];
  for (int i = tid; i < 7 * 5 * 108; i += 128) {
    int ci = i / 540, rem = i % 540, r = rem / 108, c = rem % 108;
    sIn[i] = lay[((b * 7 + ci) * HW + 2 * h + r) * HW + c];
  }
  __syncthreads();
  int co = tid >> 2, wg = tid & 3;
  int w0 = wg * 13;
  float acc[13];
#pragma unroll
  for (int j = 0; j < 13; ++j) acc[j] = 0.f;
  for (int ci = 0; ci < 7; ++ci) {
#pragma unroll
    for (int kh = 0; kh < 5; ++kh) {
      const float* row = &sIn[(ci * 5 + kh) * 108 + 2 * w0];
      float r[29];
#pragma unroll
      for (int i = 0; i < 29; ++i) r[i] = row[i];
      const float* wp = &sW[co * 175 + ci * 25 + kh * 5];
#pragma unroll
      for (int kw = 0; kw < 5; ++kw) {
        float wv = wp[kw];
#pragma unroll
        for (int j = 0; j < 13; ++j) acc[j] = fmaf(r[2 * j + kw], wv, acc[j]);
      }
    }
  }
  float* op = &out[((b * 32 + co) * 52 + h) * 52 + w0];
#pragma unroll
  for (int j = 0; j < 13; ++j) op[j] = acc[j];
}

// ------------------------------------------------------- per-channel BN stats
// grid = B*C slices of S contiguous elements; one atomic pair per block.
__global__ __launch_bounds__(256) void stats_kernel(
    const float* __restrict__ src, int S, int C,
    float* __restrict__ sumP, float* __restrict__ sumsqP) {
  int slice = blockIdx.x;
  int c = slice % C;
  const float* p = src + (size_t)slice * S;
  float s = 0.f, q = 0.f;
  for (int i = threadIdx.x; i < S; i += 256) {
    float v = p[i];
    s += v;
    q += v * v;
  }
  for (int off = 32; off; off >>= 1) {
    s += __shfl_down(s, off, 64);
    q += __shfl_down(q, off, 64);
  }
  __shared__ float ls[4], lq[4];
  int wid = threadIdx.x >> 6;
  if ((threadIdx.x & 63) == 0) { ls[wid] = s; lq[wid] = q; }
  __syncthreads();
  if (threadIdx.x == 0) {
    s = ls[0] + ls[1] + ls[2] + ls[3];
    q = lq[0] + lq[1] + lq[2] + lq[3];
    atomicAdd(&sumP[c], s);
    atomicAdd(&sumsqP[c], q);
  }
}

__global__ void bn_finalize_kernel(
    const float* __restrict__ sum, const float* __restrict__ sumsq,
    const float* __restrict__ g, const float* __restrict__ bb, float invN,
    int C, float* __restrict__ scale, float* __restrict__ shift) {
  int c = threadIdx.x;
  if (c < C) {
    float mean = sum[c] * invN;
    float var = sumsq[c] * invN - mean * mean;
    float sc = g[c] * rsqrtf(var + 1e-5f);
    scale[c] = sc;
    shift[c] = bb[c] - mean * sc;
  }
}

// -------------------------------------------------------------------- conv2
// grid (24 h, 64 b), block 128 = (co 0..63) x (wg 0..1, 12 outputs each).
// BN1+leaky applied while staging input into LDS.
__global__ __launch_bounds__(128) void conv2_kernel(
    const float* __restrict__ x1, const float* __restrict__ w2,
    const float* __restrict__ sc1, const float* __restrict__ sh1,
    float* __restrict__ out) {
  int h = blockIdx.x, b = blockIdx.y;
  __shared__ float sIn[32 * 5 * 52];  // [ci][r][c]
  __shared__ float sWs[64 * 25];      // per-ci weight slice [co][kh*5+kw]
  int tid = threadIdx.x;
  for (int i = tid; i < 32 * 5 * 52; i += 128) {
    int ci = i / 260, rem = i % 260, r = rem / 52, c = rem % 52;
    float v = x1[((b * 32 + ci) * 52 + 2 * h + r) * 52 + c];
    v = v * sc1[ci] + sh1[ci];
    sIn[i] = LEAKY(v);
  }
  int co = tid >> 1, wg = tid & 1, w0 = wg * 12;
  float acc[12];
#pragma unroll
  for (int j = 0; j < 12; ++j) acc[j] = 0.f;
  for (int ci = 0; ci < 32; ++ci) {
    __syncthreads();  // covers initial input staging + prev-iter sWs use
    for (int i = tid; i < 1600; i += 128)
      sWs[i] = w2[(i / 25) * 800 + ci * 25 + (i % 25)];
    __syncthreads();
#pragma unroll
    for (int kh = 0; kh < 5; ++kh) {
      const float* row = &sIn[(ci * 5 + kh) * 52 + 2 * w0];
      float r[27];
#pragma unroll
      for (int i = 0; i < 27; ++i) r[i] = row[i];
      const float* wp = &sWs[co * 25 + kh * 5];
#pragma unroll
      for (int kw = 0; kw < 5; ++kw) {
        float wv = wp[kw];
#pragma unroll
        for (int j = 0; j < 12; ++j) acc[j] = fmaf(r[2 * j + kw], wv, acc[j]);
      }
    }
  }
  float* op = &out[((b * 64 + co) * 24 + h) * 24 + w0];
#pragma unroll
  for (int j = 0; j < 12; ++j) op[j] = acc[j];
}

// --------------------------------- BN2+leaky + transpose (b,k) -> xT(k,b)
// grid 576 (64-k tiles), block 256. LDS 64x65 tile, both sides coalesced.
__global__ __launch_bounds__(256) void transpose_bn2_kernel(
    const float* __restrict__ x2, const float* __restrict__ sc2,
    const float* __restrict__ sh2, float* __restrict__ xT) {
  int k0 = blockIdx.x * 64;
  __shared__ float tile[64][65];
  int tid = threadIdx.x;
  int kk = tid & 63, bs = tid >> 6;  // bs 0..3
  for (int it = 0; it < 16; ++it) {
    int bb = it * 4 + bs;
    float v = x2[(size_t)bb * K1FEAT + k0 + kk];
    int c = (k0 + kk) / 576;
    v = v * sc2[c] + sh2[c];
    tile[bb][kk] = LEAKY(v);
  }
  __syncthreads();
  int b2 = tid & 63, ks = tid >> 6;
  for (int it = 0; it < 16; ++it) {
    int kk2 = it * 4 + ks;
    xT[(size_t)(k0 + kk2) * 64 + b2] = tile[b2][kk2];
  }
}

// ---------------------------------------------------------------------- fc1
// out[m][n] = sum_k xT[k][m] * w[n][k].  M=64, N=512, K=36864.
// grid (KSPLIT=96, NT=8), block 128; thread tile 4m x 8n; atomic split-K.
__global__ __launch_bounds__(128) void fc1_kernel(
    const float* __restrict__ xT, const float* __restrict__ wgt,
    float* __restrict__ out) {
  int k0 = blockIdx.x * 384;
  int n0 = blockIdx.y * 64;
  __shared__ float sx[32][64];
  __shared__ float sw[32][68];  // +4 pad
  int tid = threadIdx.x;
  int m0 = (tid & 15) * 4, ns = (tid >> 4) * 8;
  float acc[4][8];
#pragma unroll
  for (int i = 0; i < 4; ++i)
#pragma unroll
    for (int j = 0; j < 8; ++j) acc[i][j] = 0.f;
  for (int ksub = 0; ksub < 384; ksub += 32) {
    __syncthreads();
#pragma unroll
    for (int t = 0; t < 16; ++t) {
      int i = t * 128 + tid;
      sx[i >> 6][i & 63] = xT[(size_t)(k0 + ksub + (i >> 6)) * 64 + (i & 63)];
    }
#pragma unroll
    for (int t = 0; t < 16; ++t) {
      int i = t * 128 + tid;
      int nn = i >> 5, kkk = i & 31;
      sw[kkk][nn] = wgt[(size_t)(n0 + nn) * 36864 + k0 + ksub + kkk];
    }
    __syncthreads();
#pragma unroll
    for (int kk = 0; kk < 32; ++kk) {
      float xv[4], wv[8];
#pragma unroll
      for (int i = 0; i < 4; ++i) xv[i] = sx[kk][m0 + i];
#pragma unroll
      for (int j = 0; j < 8; ++j) wv[j] = sw[kk][ns + j];
#pragma unroll
      for (int i = 0; i < 4; ++i)
#pragma unroll
        for (int j = 0; j < 8; ++j) acc[i][j] = fmaf(xv[i], wv[j], acc[i][j]);
    }
  }
#pragma unroll
  for (int i = 0; i < 4; ++i)
#pragma unroll
    for (int j = 0; j < 8; ++j)
      atomicAdd(&out[(size_t)(m0 + i) * 512 + n0 + ns + j], acc[i][j]);
}

// ------------------------------------------------------- BN3 (per feature)
__global__ __launch_bounds__(64) void bn3_kernel(
    const float* __restrict__ fc1o, const float* __restrict__ g,
    const float* __restrict__ bb, float* __restrict__ scale,
    float* __restrict__ shift) {
  int f = blockIdx.x * 64 + threadIdx.x;
  float s = 0.f, q = 0.f;
  for (int m = 0; m < 64; ++m) {
    float v = fc1o[m * 512 + f];
    s += v;
    q += v * v;
  }
  float mean = s * (1.f / 64.f);
  float var = q * (1.f / 64.f) - mean * mean;
  float sc = g[f] * rsqrtf(var + 1e-5f);
  scale[f] = sc;
  shift[f] = bb[f] - mean * sc;
}

// ------------------------------------------- BN3-apply + leaky + fc2 + sigmoid
__global__ __launch_bounds__(64) void fc2_kernel(
    const float* __restrict__ fc1o, const float* __restrict__ sc,
    const float* __restrict__ sh, const float* __restrict__ w2,
    const float* __restrict__ b2, float* __restrict__ out) {
  int m = blockIdx.x;
  int f = threadIdx.x;
  float acc = 0.f;
#pragma unroll
  for (int j = 0; j < 8; ++j) {
    int ff = f + j * 64;
    float v = fc1o[m * 512 + ff] * sc[ff] + sh[ff];
    v = LEAKY(v);
    acc += v * w2[ff];
  }
  for (int off = 32; off; off >>= 1) acc += __shfl_down(acc, off, 64);
  if (f == 0) out[m] = 1.f / (1.f + expf(-(acc + b2[0])));
}

extern "C" void kernel_launch(void* const* d_in, const int* in_sizes, int n_in,
                              void* d_out, int out_size, void* d_ws,
                              size_t ws_size, hipStream_t stream) {
  const float* image = (const float*)d_in[0];
  const float* c1w = (const float*)d_in[1];
  // d_in[2] conv1_b: absorbed by BN1
  const float* bn1g = (const float*)d_in[3];
  const float* bn1b = (const float*)d_in[4];
  const float* c2w = (const float*)d_in[5];
  // d_in[6] conv2_b: absorbed by BN2
  const float* bn2g = (const float*)d_in[7];
  const float* bn2b = (const float*)d_in[8];
  const float* f1w = (const float*)d_in[9];
  // d_in[10] fc1_b: absorbed by BN3
  const float* bn3g = (const float*)d_in[11];
  const float* bn3b = (const float*)d_in[12];
  const float* f2w = (const float*)d_in[13];
  const float* f2b = (const float*)d_in[14];
  float* ws = (float*)d_ws;

  // Workspace layout (floats). Region A (layout) is dead after conv1, so
  // conv2 output + xT alias into it: 2*2,359,296 = 4,718,592 <= 5,225,472.
  float* layT = ws;                  // 5,225,472
  float* x2raw = ws;                 // alias, 2,359,296
  float* xT = ws + 2359296;          // alias, 2,359,296
  float* x1raw = ws + 5225472;       // 5,537,792
  float* fc1o = ws + 10763264;       // 32,768
  float* st = ws + 10796032;         // 192 (atomic sums, must be zeroed)
  float* bn1sum = st, *bn1sq = st + 32, *bn2sum = st + 64, *bn2sq = st + 128;
  float* coef = ws + 10796224;       // 1,216
  float* sc1 = coef, *sh1 = coef + 32;
  float* sc2 = coef + 64, *sh2 = coef + 128;
  float* sc3 = coef + 192, *sh3 = coef + 704;

  hipMemsetAsync(fc1o, 0, 32768 * sizeof(float), stream);
  hipMemsetAsync(st, 0, 192 * sizeof(float), stream);

  layout_kernel<<<dim3(108, 64), 128, 0, stream>>>(image, layT);
  conv1_kernel<<<dim3(52, 64), 128, 0, stream>>>(layT, c1w, x1raw);
  stats_kernel<<<2048, 256, 0, stream>>>(x1raw, 2704, 32, bn1sum, bn1sq);
  bn_finalize_kernel<<<1, 64, 0, stream>>>(bn1sum, bn1sq, bn1g, bn1b,
                                           1.f / 173056.f, 32, sc1, sh1);
  conv2_kernel<<<dim3(24, 64), 128, 0, stream>>>(x1raw, c2w, sc1, sh1, x2raw);
  stats_kernel<<<4096, 256, 0, stream>>>(x2raw, 576, 64, bn2sum, bn2sq);
  bn_finalize_kernel<<<1, 64, 0, stream>>>(bn2sum, bn2sq, bn2g, bn2b,
                                           1.f / 36864.f, 64, sc2, sh2);
  transpose_bn2_kernel<<<576, 256, 0, stream>>>(x2raw, sc2, sh2, xT);
  fc1_kernel<<<dim3(96, 8), 128, 0, stream>>>(xT, f1w, fc1o);
  bn3_kernel<<<8, 64, 0, stream>>>(fc1o, bn3g, bn3b, sc3, sh3);
  fc2_kernel<<<64, 64, 0, stream>>>(fc1o, sc3, sh3, f2w, f2b, (float*)d_out);
}

// Round 2
// 576.894 us; speedup vs baseline: 1.3111x; 1.3111x over previous
//
#include <hip/hip_runtime.h>
#include <hip/hip_bf16.h>

// Discriminator pipeline, fp32 throughout.
// R2: conv1/conv2 rebuilt around 4co-per-thread register tiles with
// co-contiguous (pre-transposed) weights so all LDS reads are b128 and each
// read feeds >=20 FMAs. Single-wave (64t) conv blocks -> barriers ~free.
// fc1: float4 staging, split-K into partial buffer + reduce (no atomics).
// conv/fc biases are absorbed by the following batch-norms (constant per BN
// channel cancels in x-mean), so they are intentionally not applied.

#define LEAKY(v) ((v) > 0.0f ? (v) : 0.2f * (v))
#define CLIP01(v) fminf(fmaxf((v), 0.0f), 1.0f)

constexpr int HW = 108;
constexpr int NOBJ = 16;
constexpr int NCLS = 7;
constexpr int K1FEAT = 36864;  // 64*24*24

// ---------------------------------------------------------------- layout_bbox
__global__ __launch_bounds__(128) void layout_kernel(
    const float* __restrict__ image, float* __restrict__ out) {
  int h = blockIdx.x, b = blockIdx.y;
  __shared__ float sIm[NOBJ * 11];
  int tid = threadIdx.x;
  for (int i = tid; i < NOBJ * 11; i += 128) sIm[i] = image[b * NOBJ * 11 + i];
  __syncthreads();
  int w = tid;
  if (w >= HW) return;
  float best[NCLS];
#pragma unroll
  for (int c = 0; c < NCLS; ++c) best[c] = 0.0f;
  float fw = (float)w, fh = (float)h;
  for (int o = 0; o < NOBJ; ++o) {
    const float* p = &sIm[o * 11];
    float xc = p[0] * 108.0f, yc = p[1] * 108.0f;
    float wd = p[2] * 108.0f, hd = p[3] * 108.0f;
    float x1 = xc - 0.5f * wd, x2 = xc + 0.5f * wd;
    float y1 = yc - 0.5f * hd, y2 = yc + 0.5f * hd;
    float x1d = fw - x1, x2d = x2 - fw;
    float y1d = fh - y1, y2d = y2 - fh;
    float yband = CLIP01(y1d) * CLIP01(y2d);
    float xband = CLIP01(x1d) * CLIP01(x2d);
    float x1l = fmaxf(1.0f - fabsf(x1d), 0.0f) * yband;
    float x2l = fmaxf(1.0f - fabsf(x2d), 0.0f) * yband;
    float y1l = fmaxf(1.0f - fabsf(y1d), 0.0f) * xband;
    float y2l = fmaxf(1.0f - fabsf(y2d), 0.0f) * xband;
    float xy = fmaxf(fmaxf(x1l, x2l), fmaxf(y1l, y2l));
#pragma unroll
    for (int c = 0; c < NCLS; ++c) best[c] = fmaxf(best[c], xy * p[4 + c]);
  }
#pragma unroll
  for (int c = 0; c < NCLS; ++c)
    out[((b * NCLS + c) * HW + h) * HW + w] = best[c];
}

// ------------------------------------------------- weight transposes (tiny)
// wT1[ci][p][co32] = w1[co][ci][p]   (p = kh*5+kw, 5600 elements)
__global__ void wprep1_kernel(const float* __restrict__ w1,
                              float* __restrict__ wT1) {
  int i = blockIdx.x * 256 + threadIdx.x;
  if (i < 5600) {
    int co = i & 31, p = (i >> 5) % 25, ci = i / 800;
    wT1[i] = w1[co * 175 + ci * 25 + p];
  }
}
// wT2[ci][p][co64] = w2[co][ci][p]   (51200 elements)
__global__ void wprep2_kernel(const float* __restrict__ w2,
                              float* __restrict__ wT2) {
  int i = blockIdx.x * 256 + threadIdx.x;
  int co = i & 63, p = (i >> 6) % 25, ci = i / 1600;
  wT2[i] = w2[co * 800 + ci * 25 + p];
}

// -------------------------------------------------------------------- conv1
// grid (26 row-pairs, 64 b), block 64 (1 wave).
// thread: cg=tid>>3 (4 co), wg=(tid>>1)&3 (13 w), hg=tid&1 (oh row).
// All weights in LDS once (co-contiguous): inner loop reads are b128.
__global__ __launch_bounds__(64) void conv1_kernel(
    const float* __restrict__ lay, const float* __restrict__ wT1,
    float* __restrict__ out) {
  int bx = blockIdx.x, b = blockIdx.y;
  __shared__ float sIn[7 * 7 * 108];  // [ci][r7][c108] rows 4bx..4bx+6
  __shared__ float sW[7 * 25 * 32];   // [ci][p][co]
  int tid = threadIdx.x;
  for (int i = tid; i < 5292; i += 64) {
    int ci = i / 756, rem = i % 756, r = rem / 108, c = rem - r * 108;
    sIn[i] = lay[((b * 7 + ci) * HW + 4 * bx + r) * HW + c];
  }
  {
    const float4* w4 = (const float4*)wT1;
    float4* s4 = (float4*)sW;
#pragma unroll
    for (int t = 0; t < 22; ++t) {
      int i = t * 64 + tid;
      if (i < 1400) s4[i] = w4[i];
    }
  }
  __syncthreads();
  int co0 = (tid >> 3) * 4;
  int w0 = ((tid >> 1) & 3) * 13;
  int hg = tid & 1;
  int oh = 2 * bx + hg;
  float acc[4][13];
#pragma unroll
  for (int c = 0; c < 4; ++c)
#pragma unroll
    for (int j = 0; j < 13; ++j) acc[c][j] = 0.f;
  for (int ci = 0; ci < 7; ++ci) {
#pragma unroll
    for (int kh = 0; kh < 5; ++kh) {
      const float* row = &sIn[ci * 756 + (2 * hg + kh) * 108 + 2 * w0];
      float r[29];
#pragma unroll
      for (int i = 0; i < 29; ++i) r[i] = row[i];
#pragma unroll
      for (int kw = 0; kw < 5; ++kw) {
        float4 wv = *(const float4*)&sW[ci * 800 + (kh * 5 + kw) * 32 + co0];
#pragma unroll
        for (int j = 0; j < 13; ++j) {
          float x = r[2 * j + kw];
          acc[0][j] = fmaf(x, wv.x, acc[0][j]);
          acc[1][j] = fmaf(x, wv.y, acc[1][j]);
          acc[2][j] = fmaf(x, wv.z, acc[2][j]);
          acc[3][j] = fmaf(x, wv.w, acc[3][j]);
        }
      }
    }
  }
#pragma unroll
  for (int c = 0; c < 4; ++c) {
    float* op = &out[((b * 32 + co0 + c) * 52 + oh) * 52 + w0];
#pragma unroll
    for (int j = 0; j < 13; ++j) op[j] = acc[c][j];
  }
}

// ------------------------------------------------------- per-channel BN stats
__global__ __launch_bounds__(256) void stats_kernel(
    const float* __restrict__ src, int S, int C,
    float* __restrict__ sumP, float* __restrict__ sumsqP) {
  int slice = blockIdx.x;
  int c = slice % C;
  const float* p = src + (size_t)slice * S;
  float s = 0.f, q = 0.f;
  for (int i = threadIdx.x; i < S; i += 256) {
    float v = p[i];
    s += v;
    q += v * v;
  }
  for (int off = 32; off; off >>= 1) {
    s += __shfl_down(s, off, 64);
    q += __shfl_down(q, off, 64);
  }
  __shared__ float ls[4], lq[4];
  int wid = threadIdx.x >> 6;
  if ((threadIdx.x & 63) == 0) { ls[wid] = s; lq[wid] = q; }
  __syncthreads();
  if (threadIdx.x == 0) {
    s = ls[0] + ls[1] + ls[2] + ls[3];
    q = lq[0] + lq[1] + lq[2] + lq[3];
    atomicAdd(&sumP[c], s);
    atomicAdd(&sumsqP[c], q);
  }
}

__global__ void bn_finalize_kernel(
    const float* __restrict__ sum, const float* __restrict__ sumsq,
    const float* __restrict__ g, const float* __restrict__ bb, float invN,
    int C, float* __restrict__ scale, float* __restrict__ shift) {
  int c = threadIdx.x;
  if (c < C) {
    float mean = sum[c] * invN;
    float var = sumsq[c] * invN - mean * mean;
    float sc = g[c] * rsqrtf(var + 1e-5f);
    scale[c] = sc;
    shift[c] = bb[c] - mean * sc;
  }
}

// -------------------------------------------------------------------- conv2
// grid (24 oh, 64 b), block 64 (1 wave).
// thread: cg=tid>>2 (4 co of 64), wg=tid&3 (6 w of 24). acc 4x6.
// Per-ci weight slice staged from pre-transposed wT2 (coalesced float4);
// inner reads: 1 b128 weight per (kh,kw) + ~4 wide input reads per (kh).
__global__ __launch_bounds__(64) void conv2_kernel(
    const float* __restrict__ x1, const float* __restrict__ wT2,
    const float* __restrict__ sc1, const float* __restrict__ sh1,
    float* __restrict__ out) {
  int oh = blockIdx.x, b = blockIdx.y;
  __shared__ float sIn[32 * 5 * 52];  // [ci][r5][c52]
  __shared__ float sW[25 * 64];       // [p][co]
  int tid = threadIdx.x;
  for (int i = tid; i < 8320; i += 64) {
    int ci = i / 260, rem = i % 260, r = rem / 52, c = rem - r * 52;
    float v = x1[((b * 32 + ci) * 52 + 2 * oh + r) * 52 + c];
    v = v * sc1[ci] + sh1[ci];
    sIn[i] = LEAKY(v);
  }
  int co0 = (tid >> 2) * 4;
  int w0 = (tid & 3) * 6;
  float acc[4][6];
#pragma unroll
  for (int c = 0; c < 4; ++c)
#pragma unroll
    for (int j = 0; j < 6; ++j) acc[c][j] = 0.f;
  for (int ci = 0; ci < 32; ++ci) {
    __syncthreads();  // 1-wave block: compiles to waitcnt + trivial barrier
    {
      const float4* wp4 = (const float4*)&wT2[ci * 1600];
      float4* s4 = (float4*)sW;
#pragma unroll
      for (int t = 0; t < 7; ++t) {
        int i = t * 64 + tid;
        if (i < 400) s4[i] = wp4[i];
      }
    }
    __syncthreads();
#pragma unroll
    for (int kh = 0; kh < 5; ++kh) {
      const float* row = &sIn[(ci * 5 + kh) * 52 + 2 * w0];
      float r[15];
#pragma unroll
      for (int i = 0; i < 15; ++i) r[i] = row[i];
#pragma unroll
      for (int kw = 0; kw < 5; ++kw) {
        float4 wv = *(const float4*)&sW[(kh * 5 + kw) * 64 + co0];
#pragma unroll
        for (int j = 0; j < 6; ++j) {
          float x = r[2 * j + kw];
          acc[0][j] = fmaf(x, wv.x, acc[0][j]);
          acc[1][j] = fmaf(x, wv.y, acc[1][j]);
          acc[2][j] = fmaf(x, wv.z, acc[2][j]);
          acc[3][j] = fmaf(x, wv.w, acc[3][j]);
        }
      }
    }
  }
#pragma unroll
  for (int c = 0; c < 4; ++c) {
    float* op = &out[((b * 64 + co0 + c) * 24 + oh) * 24 + w0];
#pragma unroll
    for (int j = 0; j < 6; ++j) op[j] = acc[c][j];
  }
}

// --------------------------------- BN2+leaky + transpose (b,k) -> xT(k,b)
__global__ __launch_bounds__(256) void transpose_bn2_kernel(
    const float* __restrict__ x2, const float* __restrict__ sc2,
    const float* __restrict__ sh2, float* __restrict__ xT) {
  int k0 = blockIdx.x * 64;
  __shared__ float tile[64][65];
  int tid = threadIdx.x;
  int kk = tid & 63, bs = tid >> 6;
  for (int it = 0; it < 16; ++it) {
    int bb = it * 4 + bs;
    float v = x2[(size_t)bb * K1FEAT + k0 + kk];
    int c = (k0 + kk) / 576;
    v = v * sc2[c] + sh2[c];
    tile[bb][kk] = LEAKY(v);
  }
  __syncthreads();
  int b2 = tid & 63, ks = tid >> 6;
  for (int it = 0; it < 16; ++it) {
    int kk2 = it * 4 + ks;
    xT[(size_t)(k0 + kk2) * 64 + b2] = tile[b2][kk2];
  }
}

// ---------------------------------------------------------------------- fc1
// part[ks][m][n] = sum over 576-K chunk. grid (64 ks, 8 nt), block 128.
__global__ __launch_bounds__(128) void fc1_kernel(
    const float* __restrict__ xT, const float* __restrict__ wgt,
    float* __restrict__ part) {
  int ks = blockIdx.x;
  int n0 = blockIdx.y * 64;
  int k0 = ks * 576;
  __shared__ float sx[32][64];
  __shared__ float sw[32][68];
  int tid = threadIdx.x;
  int m0 = (tid & 15) * 4, ns = (tid >> 4) * 8;
  float acc[4][8];
#pragma unroll
  for (int i = 0; i < 4; ++i)
#pragma unroll
    for (int j = 0; j < 8; ++j) acc[i][j] = 0.f;
  for (int kt = 0; kt < 576; kt += 32) {
    __syncthreads();
    {
      const float4* xs = (const float4*)&xT[(size_t)(k0 + kt) * 64];
      float4* s4 = (float4*)sx;
#pragma unroll
      for (int t = 0; t < 4; ++t) {
        int i = t * 128 + tid;
        s4[i] = xs[i];
      }
#pragma unroll
      for (int t = 0; t < 4; ++t) {
        int f = t * 128 + tid;
        int nn = f >> 3, kq = (f & 7) * 4;
        float4 v =
            *(const float4*)&wgt[(size_t)(n0 + nn) * 36864 + k0 + kt + kq];
        sw[kq + 0][nn] = v.x;
        sw[kq + 1][nn] = v.y;
        sw[kq + 2][nn] = v.z;
        sw[kq + 3][nn] = v.w;
      }
    }
    __syncthreads();
#pragma unroll
    for (int kk = 0; kk < 32; ++kk) {
      float4 xv = *(const float4*)&sx[kk][m0];
      float4 wa = *(const float4*)&sw[kk][ns];
      float4 wb = *(const float4*)&sw[kk][ns + 4];
      float xr[4] = {xv.x, xv.y, xv.z, xv.w};
      float wr[8] = {wa.x, wa.y, wa.z, wa.w, wb.x, wb.y, wb.z, wb.w};
#pragma unroll
      for (int i = 0; i < 4; ++i)
#pragma unroll
        for (int j = 0; j < 8; ++j)
          acc[i][j] = fmaf(xr[i], wr[j], acc[i][j]);
    }
  }
  float* pp = &part[(size_t)ks * 32768];
#pragma unroll
  for (int i = 0; i < 4; ++i)
#pragma unroll
    for (int j = 0; j < 8; ++j)
      pp[(m0 + i) * 512 + n0 + ns + j] = acc[i][j];
}

// sum the 64 split-K partials
__global__ __launch_bounds__(256) void fc1_reduce_kernel(
    const float* __restrict__ part, float* __restrict__ out) {
  int i = blockIdx.x * 256 + threadIdx.x;  // 0..32767
  float s = 0.f;
#pragma unroll 8
  for (int ks = 0; ks < 64; ++ks) s += part[(size_t)ks * 32768 + i];
  out[i] = s;
}

// ------------------------------------------------------- BN3 (per feature)
__global__ __launch_bounds__(64) void bn3_kernel(
    const float* __restrict__ fc1o, const float* __restrict__ g,
    const float* __restrict__ bb, float* __restrict__ scale,
    float* __restrict__ shift) {
  int f = blockIdx.x * 64 + threadIdx.x;
  float s = 0.f, q = 0.f;
  for (int m = 0; m < 64; ++m) {
    float v = fc1o[m * 512 + f];
    s += v;
    q += v * v;
  }
  float mean = s * (1.f / 64.f);
  float var = q * (1.f / 64.f) - mean * mean;
  float sc = g[f] * rsqrtf(var + 1e-5f);
  scale[f] = sc;
  shift[f] = bb[f] - mean * sc;
}

// ------------------------------------------- BN3-apply + leaky + fc2 + sigmoid
__global__ __launch_bounds__(64) void fc2_kernel(
    const float* __restrict__ fc1o, const float* __restrict__ sc,
    const float* __restrict__ sh, const float* __restrict__ w2,
    const float* __restrict__ b2, float* __restrict__ out) {
  int m = blockIdx.x;
  int f = threadIdx.x;
  float acc = 0.f;
#pragma unroll
  for (int j = 0; j < 8; ++j) {
    int ff = f + j * 64;
    float v = fc1o[m * 512 + ff] * sc[ff] + sh[ff];
    v = LEAKY(v);
    acc += v * w2[ff];
  }
  for (int off = 32; off; off >>= 1) acc += __shfl_down(acc, off, 64);
  if (f == 0) out[m] = 1.f / (1.f + expf(-(acc + b2[0])));
}

extern "C" void kernel_launch(void* const* d_in, const int* in_sizes, int n_in,
                              void* d_out, int out_size, void* d_ws,
                              size_t ws_size, hipStream_t stream) {
  const float* image = (const float*)d_in[0];
  const float* c1w = (const float*)d_in[1];
  const float* bn1g = (const float*)d_in[3];
  const float* bn1b = (const float*)d_in[4];
  const float* c2w = (const float*)d_in[5];
  const float* bn2g = (const float*)d_in[7];
  const float* bn2b = (const float*)d_in[8];
  const float* f1w = (const float*)d_in[9];
  const float* bn3g = (const float*)d_in[11];
  const float* bn3b = (const float*)d_in[12];
  const float* f2w = (const float*)d_in[13];
  const float* f2b = (const float*)d_in[14];
  float* ws = (float*)d_ws;

  // Workspace (floats). Region A (layT, 5,225,472) is dead after conv1:
  //   x2 (2,359,296) + xT (2,359,296) + wT2 (51,200) alias into it.
  // Region B (x1raw, 5,537,792) is dead after conv2: fc1part (2,097,152)
  //   aliases into it.
  float* layT = ws;
  float* x2raw = ws;
  float* xT = ws + 2359296;
  float* wT2 = ws + 4718592;       // written after conv1, read by conv2
  float* x1raw = ws + 5225472;
  float* fc1part = ws + 5225472;   // written after transpose
  float* fc1o = ws + 10763264;     // 32,768
  float* st = ws + 10796032;       // 192 (atomic sums, zeroed)
  float* bn1sum = st, *bn1sq = st + 32, *bn2sum = st + 64, *bn2sq = st + 128;
  float* coef = ws + 10796224;     // 1,216
  float* sc1 = coef, *sh1 = coef + 32;
  float* sc2 = coef + 64, *sh2 = coef + 128;
  float* sc3 = coef + 192, *sh3 = coef + 704;
  float* wT1 = ws + 10797440;      // 5,600

  hipMemsetAsync(st, 0, 192 * sizeof(float), stream);

  wprep1_kernel<<<22, 256, 0, stream>>>(c1w, wT1);
  layout_kernel<<<dim3(108, 64), 128, 0, stream>>>(image, layT);
  conv1_kernel<<<dim3(26, 64), 64, 0, stream>>>(layT, wT1, x1raw);
  wprep2_kernel<<<200, 256, 0, stream>>>(c2w, wT2);  // layT dead now
  stats_kernel<<<2048, 256, 0, stream>>>(x1raw, 2704, 32, bn1sum, bn1sq);
  bn_finalize_kernel<<<1, 64, 0, stream>>>(bn1sum, bn1sq, bn1g, bn1b,
                                           1.f / 173056.f, 32, sc1, sh1);
  conv2_kernel<<<dim3(24, 64), 64, 0, stream>>>(x1raw, wT2, sc1, sh1, x2raw);
  stats_kernel<<<4096, 256, 0, stream>>>(x2raw, 576, 64, bn2sum, bn2sq);
  bn_finalize_kernel<<<1, 64, 0, stream>>>(bn2sum, bn2sq, bn2g, bn2b,
                                           1.f / 36864.f, 64, sc2, sh2);
  transpose_bn2_kernel<<<576, 256, 0, stream>>>(x2raw, sc2, sh2, xT);
  fc1_kernel<<<dim3(64, 8), 128, 0, stream>>>(xT, f1w, fc1part);
  fc1_reduce_kernel<<<128, 256, 0, stream>>>(fc1part, fc1o);
  bn3_kernel<<<8, 64, 0, stream>>>(fc1o, bn3g, bn3b, sc3, sh3);
  fc2_kernel<<<64, 64, 0, stream>>>(fc1o, sc3, sh3, f2w, f2b, (float*)d_out);
}

// Round 3
// 388.673 us; speedup vs baseline: 1.9461x; 1.4843x over previous
//
#include <hip/hip_runtime.h>
#include <hip/hip_bf16.h>

// Discriminator pipeline, fp32 throughout.
// R3: occupancy fix. conv2: 4-wave blocks, ci-split across waves, input taps
// direct from global (L1 broadcast), wave-private per-ci weight LDS slices
// (no inner barriers), cross-wave LDS reduce. BN1+leaky applied by a separate
// in-place pass so conv2 inner loop is pure FMA. conv1: 1-oh blocks with
// per-ci weight streaming (18KB LDS -> 8 waves/CU). fc1: 128-way split-K.
// conv/fc biases absorbed by the following batch-norms (constant per channel
// cancels in x-mean), intentionally not applied.

#define LEAKY(v) (fmaxf((v), 0.2f * (v)))
#define CLIP01(v) fminf(fmaxf((v), 0.0f), 1.0f)

constexpr int HW = 108;
constexpr int NOBJ = 16;
constexpr int NCLS = 7;
constexpr int K1FEAT = 36864;  // 64*24*24

// ---------------------------------------------------------------- layout_bbox
__global__ __launch_bounds__(128) void layout_kernel(
    const float* __restrict__ image, float* __restrict__ out) {
  int h = blockIdx.x, b = blockIdx.y;
  __shared__ float sIm[NOBJ * 11];
  int tid = threadIdx.x;
  for (int i = tid; i < NOBJ * 11; i += 128) sIm[i] = image[b * NOBJ * 11 + i];
  __syncthreads();
  int w = tid;
  if (w >= HW) return;
  float best[NCLS];
#pragma unroll
  for (int c = 0; c < NCLS; ++c) best[c] = 0.0f;
  float fw = (float)w, fh = (float)h;
  for (int o = 0; o < NOBJ; ++o) {
    const float* p = &sIm[o * 11];
    float xc = p[0] * 108.0f, yc = p[1] * 108.0f;
    float wd = p[2] * 108.0f, hd = p[3] * 108.0f;
    float x1 = xc - 0.5f * wd, x2 = xc + 0.5f * wd;
    float y1 = yc - 0.5f * hd, y2 = yc + 0.5f * hd;
    float x1d = fw - x1, x2d = x2 - fw;
    float y1d = fh - y1, y2d = y2 - fh;
    float yband = CLIP01(y1d) * CLIP01(y2d);
    float xband = CLIP01(x1d) * CLIP01(x2d);
    float x1l = fmaxf(1.0f - fabsf(x1d), 0.0f) * yband;
    float x2l = fmaxf(1.0f - fabsf(x2d), 0.0f) * yband;
    float y1l = fmaxf(1.0f - fabsf(y1d), 0.0f) * xband;
    float y2l = fmaxf(1.0f - fabsf(y2d), 0.0f) * xband;
    float xy = fmaxf(fmaxf(x1l, x2l), fmaxf(y1l, y2l));
#pragma unroll
    for (int c = 0; c < NCLS; ++c) best[c] = fmaxf(best[c], xy * p[4 + c]);
  }
#pragma unroll
  for (int c = 0; c < NCLS; ++c)
    out[((b * NCLS + c) * HW + h) * HW + w] = best[c];
}

// ------------------------------------------------- weight transposes (tiny)
// wT1[ci][p][co32] = w1[co][ci][p]   (p = kh*5+kw, 5600 elements)
__global__ void wprep1_kernel(const float* __restrict__ w1,
                              float* __restrict__ wT1) {
  int i = blockIdx.x * 256 + threadIdx.x;
  if (i < 5600) {
    int co = i & 31, p = (i >> 5) % 25, ci = i / 800;
    wT1[i] = w1[co * 175 + ci * 25 + p];
  }
}
// wT2[ci][p][co64] = w2[co][ci][p]   (51200 elements)
__global__ void wprep2_kernel(const float* __restrict__ w2,
                              float* __restrict__ wT2) {
  int i = blockIdx.x * 256 + threadIdx.x;
  int co = i & 63, p = (i >> 6) % 25, ci = i / 1600;
  wT2[i] = w2[co * 800 + ci * 25 + p];
}

// -------------------------------------------------------------------- conv1
// grid (52 oh, 64 b), block 64 (1 wave). thread: co0=(tid>>2)*2 (2 co),
// w0=(tid&3)*13 (13 w). Per-ci weight streaming keeps LDS at 18.3KB
// -> 8 blocks/CU resident.
__global__ __launch_bounds__(64) void conv1_kernel(
    const float* __restrict__ lay, const float* __restrict__ wT1,
    float* __restrict__ out) {
  int oh = blockIdx.x, b = blockIdx.y;
  __shared__ float sIn[7 * 5 * 108];  // [ci][r5][c108], rows 2oh..2oh+4
  __shared__ float sW[25 * 32];       // [p][co] for current ci
  int tid = threadIdx.x;
  for (int i = tid; i < 3780; i += 64) {
    int ci = i / 540, rem = i % 540, r = rem / 108, c = rem - r * 108;
    sIn[i] = lay[((b * 7 + ci) * HW + 2 * oh + r) * HW + c];
  }
  __syncthreads();
  int co0 = (tid >> 2) * 2;
  int w0 = (tid & 3) * 13;
  float acc[2][13];
#pragma unroll
  for (int c = 0; c < 2; ++c)
#pragma unroll
    for (int j = 0; j < 13; ++j) acc[c][j] = 0.f;
  const float4* wAll4 = (const float4*)wT1;
  float4* sW4 = (float4*)sW;
  for (int ci = 0; ci < 7; ++ci) {
    // wave-private block (1 wave): LDS ops in order, no barrier needed
#pragma unroll
    for (int t = 0; t < 4; ++t) {
      int i = t * 64 + tid;
      if (i < 200) sW4[i] = wAll4[ci * 200 + i];
    }
#pragma unroll
    for (int kh = 0; kh < 5; ++kh) {
      const float2* rp2 = (const float2*)&sIn[ci * 540 + kh * 108 + 2 * w0];
      float r[30];
#pragma unroll
      for (int i = 0; i < 15; ++i) {
        float2 v = rp2[i];
        r[2 * i] = v.x;
        r[2 * i + 1] = v.y;
      }
#pragma unroll
      for (int kw = 0; kw < 5; ++kw) {
        float2 wv = *(const float2*)&sW[(kh * 5 + kw) * 32 + co0];
#pragma unroll
        for (int j = 0; j < 13; ++j) {
          float x = r[2 * j + kw];
          acc[0][j] = fmaf(x, wv.x, acc[0][j]);
          acc[1][j] = fmaf(x, wv.y, acc[1][j]);
        }
      }
    }
  }
#pragma unroll
  for (int c = 0; c < 2; ++c) {
    float* op = &out[((b * 32 + co0 + c) * 52 + oh) * 52 + w0];
#pragma unroll
    for (int j = 0; j < 13; ++j) op[j] = acc[c][j];
  }
}

// ------------------------------------------------------- per-channel BN stats
__global__ __launch_bounds__(256) void stats_kernel(
    const float* __restrict__ src, int S, int C,
    float* __restrict__ sumP, float* __restrict__ sumsqP) {
  int slice = blockIdx.x;
  int c = slice % C;
  const float* p = src + (size_t)slice * S;
  float s = 0.f, q = 0.f;
  for (int i = threadIdx.x; i < S; i += 256) {
    float v = p[i];
    s += v;
    q += v * v;
  }
  for (int off = 32; off; off >>= 1) {
    s += __shfl_down(s, off, 64);
    q += __shfl_down(q, off, 64);
  }
  __shared__ float ls[4], lq[4];
  int wid = threadIdx.x >> 6;
  if ((threadIdx.x & 63) == 0) { ls[wid] = s; lq[wid] = q; }
  __syncthreads();
  if (threadIdx.x == 0) {
    s = ls[0] + ls[1] + ls[2] + ls[3];
    q = lq[0] + lq[1] + lq[2] + lq[3];
    atomicAdd(&sumP[c], s);
    atomicAdd(&sumsqP[c], q);
  }
}

__global__ void bn_finalize_kernel(
    const float* __restrict__ sum, const float* __restrict__ sumsq,
    const float* __restrict__ g, const float* __restrict__ bb, float invN,
    int C, float* __restrict__ scale, float* __restrict__ shift) {
  int c = threadIdx.x;
  if (c < C) {
    float mean = sum[c] * invN;
    float var = sumsq[c] * invN - mean * mean;
    float sc = g[c] * rsqrtf(var + 1e-5f);
    scale[c] = sc;
    shift[c] = bb[c] - mean * sc;
  }
}

// ------------------------------------- BN1-apply + leaky, in place on x1raw
__global__ __launch_bounds__(256) void bnapply1_kernel(
    float* __restrict__ x1, const float* __restrict__ sc,
    const float* __restrict__ sh) {
  int idx = blockIdx.x * 256 + threadIdx.x;  // f4 index, 1,384,448 total
  int ci = (idx / 676) & 31;                 // 2704 floats per (b,ci) plane
  float s = sc[ci], t = sh[ci];
  float4 v = ((const float4*)x1)[idx];
  v.x = LEAKY(fmaf(v.x, s, t));
  v.y = LEAKY(fmaf(v.y, s, t));
  v.z = LEAKY(fmaf(v.z, s, t));
  v.w = LEAKY(fmaf(v.w, s, t));
  ((float4*)x1)[idx] = v;
}

// -------------------------------------------------------------------- conv2
// grid (24 oh, 64 b), block 256 (4 waves). lane: co0=((tid>>2)&15)*4,
// w0=(tid&3)*6; wave wv handles ci in [wv*8, wv*8+8). Input taps direct from
// global (16-lane broadcast, 16B aligned). Weights per-ci in wave-private LDS
// slice (no barriers in main loop). Cross-wave reduce via LDS at the end.
__global__ __launch_bounds__(256) void conv2_kernel(
    const float* __restrict__ x1, const float* __restrict__ wT2,
    float* __restrict__ out) {
  int oh = blockIdx.x, b = blockIdx.y;
  __shared__ float sBuf[6400];  // sW: [wave][1600]; later sRed: [wave][1536]
  int tid = threadIdx.x;
  int lane = tid & 63, wv = tid >> 6;
  int co0 = ((tid >> 2) & 15) * 4;
  int w0 = (tid & 3) * 6;
  float acc[4][6];
#pragma unroll
  for (int c = 0; c < 4; ++c)
#pragma unroll
    for (int j = 0; j < 6; ++j) acc[c][j] = 0.f;
  float4* sW4 = (float4*)sBuf;
  for (int ci8 = 0; ci8 < 8; ++ci8) {
    int ci = wv * 8 + ci8;
    const float4* wp4 = (const float4*)&wT2[ci * 1600];
#pragma unroll
    for (int t = 0; t < 7; ++t) {
      int i = t * 64 + lane;
      if (i < 400) sW4[wv * 400 + i] = wp4[i];
    }
    // same-wave LDS in-order: writes visible to own reads without barrier
    const float* rowbase = &x1[((b * 32 + ci) * 52 + 2 * oh) * 52 + 2 * w0];
#pragma unroll
    for (int kh = 0; kh < 5; ++kh) {
      const float4* rp = (const float4*)(rowbase + kh * 52);
      float4 ra = rp[0], rb = rp[1], rc = rp[2], rd = rp[3];
      float r[16] = {ra.x, ra.y, ra.z, ra.w, rb.x, rb.y, rb.z, rb.w,
                     rc.x, rc.y, rc.z, rc.w, rd.x, rd.y, rd.z, rd.w};
#pragma unroll
      for (int kw = 0; kw < 5; ++kw) {
        float4 wv4 =
            *(const float4*)&sBuf[wv * 1600 + (kh * 5 + kw) * 64 + co0];
#pragma unroll
        for (int j = 0; j < 6; ++j) {
          float x = r[2 * j + kw];
          acc[0][j] = fmaf(x, wv4.x, acc[0][j]);
          acc[1][j] = fmaf(x, wv4.y, acc[1][j]);
          acc[2][j] = fmaf(x, wv4.z, acc[2][j]);
          acc[3][j] = fmaf(x, wv4.w, acc[3][j]);
        }
      }
    }
  }
  __syncthreads();  // protect other waves' sW reads before aliasing as sRed
#pragma unroll
  for (int c = 0; c < 4; ++c)
#pragma unroll
    for (int j = 0; j < 6; ++j)
      sBuf[wv * 1536 + lane * 24 + c * 6 + j] = acc[c][j];
  __syncthreads();
  // 1536 outputs, 6 per thread: o -> (src lane ls, slot j)
#pragma unroll
  for (int u = 0; u < 6; ++u) {
    int o = tid * 6 + u;
    int ls = o / 24, j = o - ls * 24;
    float s = sBuf[ls * 24 + j] + sBuf[1536 + ls * 24 + j] +
              sBuf[3072 + ls * 24 + j] + sBuf[4608 + ls * 24 + j];
    int co = (ls >> 2) * 4 + j / 6;
    int w = (ls & 3) * 6 + j % 6;
    out[((b * 64 + co) * 24 + oh) * 24 + w] = s;
  }
}

// --------------------------------- BN2+leaky + transpose (b,k) -> xT(k,b)
__global__ __launch_bounds__(256) void transpose_bn2_kernel(
    const float* __restrict__ x2, const float* __restrict__ sc2,
    const float* __restrict__ sh2, float* __restrict__ xT) {
  int k0 = blockIdx.x * 64;
  __shared__ float tile[64][65];
  int tid = threadIdx.x;
  int kk = tid & 63, bs = tid >> 6;
  for (int it = 0; it < 16; ++it) {
    int bb = it * 4 + bs;
    float v = x2[(size_t)bb * K1FEAT + k0 + kk];
    int c = (k0 + kk) / 576;
    v = v * sc2[c] + sh2[c];
    tile[bb][kk] = LEAKY(v);
  }
  __syncthreads();
  int b2 = tid & 63, ks = tid >> 6;
  for (int it = 0; it < 16; ++it) {
    int kk2 = it * 4 + ks;
    xT[(size_t)(k0 + kk2) * 64 + b2] = tile[b2][kk2];
  }
}

// ---------------------------------------------------------------------- fc1
// part[ks][m][n], 128-way split-K (288 K each). grid (128, 8), block 128.
__global__ __launch_bounds__(128) void fc1_kernel(
    const float* __restrict__ xT, const float* __restrict__ wgt,
    float* __restrict__ part) {
  int ks = blockIdx.x;
  int n0 = blockIdx.y * 64;
  int k0 = ks * 288;
  __shared__ float sx[32][64];
  __shared__ float sw[32][68];
  int tid = threadIdx.x;
  int m0 = (tid & 15) * 4, ns = (tid >> 4) * 8;
  float acc[4][8];
#pragma unroll
  for (int i = 0; i < 4; ++i)
#pragma unroll
    for (int j = 0; j < 8; ++j) acc[i][j] = 0.f;
  for (int kt = 0; kt < 288; kt += 32) {
    __syncthreads();
    {
      const float4* xs = (const float4*)&xT[(size_t)(k0 + kt) * 64];
      float4* s4 = (float4*)sx;
#pragma unroll
      for (int t = 0; t < 4; ++t) {
        int i = t * 128 + tid;
        s4[i] = xs[i];
      }
#pragma unroll
      for (int t = 0; t < 4; ++t) {
        int f = t * 128 + tid;
        int nn = f >> 3, kq = (f & 7) * 4;
        float4 v =
            *(const float4*)&wgt[(size_t)(n0 + nn) * 36864 + k0 + kt + kq];
        sw[kq + 0][nn] = v.x;
        sw[kq + 1][nn] = v.y;
        sw[kq + 2][nn] = v.z;
        sw[kq + 3][nn] = v.w;
      }
    }
    __syncthreads();
#pragma unroll
    for (int kk = 0; kk < 32; ++kk) {
      float4 xv = *(const float4*)&sx[kk][m0];
      float4 wa = *(const float4*)&sw[kk][ns];
      float4 wb = *(const float4*)&sw[kk][ns + 4];
      float xr[4] = {xv.x, xv.y, xv.z, xv.w};
      float wr[8] = {wa.x, wa.y, wa.z, wa.w, wb.x, wb.y, wb.z, wb.w};
#pragma unroll
      for (int i = 0; i < 4; ++i)
#pragma unroll
        for (int j = 0; j < 8; ++j)
          acc[i][j] = fmaf(xr[i], wr[j], acc[i][j]);
    }
  }
  float* pp = &part[(size_t)ks * 32768];
#pragma unroll
  for (int i = 0; i < 4; ++i)
#pragma unroll
    for (int j = 0; j < 8; ++j)
      pp[(m0 + i) * 512 + n0 + ns + j] = acc[i][j];
}

// sum the 128 split-K partials
__global__ __launch_bounds__(256) void fc1_reduce_kernel(
    const float* __restrict__ part, float* __restrict__ out) {
  int i = blockIdx.x * 256 + threadIdx.x;  // 0..32767
  float s = 0.f;
#pragma unroll 8
  for (int ks = 0; ks < 128; ++ks) s += part[(size_t)ks * 32768 + i];
  out[i] = s;
}

// ------------------------------------------------------- BN3 (per feature)
__global__ __launch_bounds__(64) void bn3_kernel(
    const float* __restrict__ fc1o, const float* __restrict__ g,
    const float* __restrict__ bb, float* __restrict__ scale,
    float* __restrict__ shift) {
  int f = blockIdx.x * 64 + threadIdx.x;
  float s = 0.f, q = 0.f;
  for (int m = 0; m < 64; ++m) {
    float v = fc1o[m * 512 + f];
    s += v;
    q += v * v;
  }
  float mean = s * (1.f / 64.f);
  float var = q * (1.f / 64.f) - mean * mean;
  float sc = g[f] * rsqrtf(var + 1e-5f);
  scale[f] = sc;
  shift[f] = bb[f] - mean * sc;
}

// ------------------------------------------- BN3-apply + leaky + fc2 + sigmoid
__global__ __launch_bounds__(64) void fc2_kernel(
    const float* __restrict__ fc1o, const float* __restrict__ sc,
    const float* __restrict__ sh, const float* __restrict__ w2,
    const float* __restrict__ b2, float* __restrict__ out) {
  int m = blockIdx.x;
  int f = threadIdx.x;
  float acc = 0.f;
#pragma unroll
  for (int j = 0; j < 8; ++j) {
    int ff = f + j * 64;
    float v = fc1o[m * 512 + ff] * sc[ff] + sh[ff];
    v = LEAKY(v);
    acc += v * w2[ff];
  }
  for (int off = 32; off; off >>= 1) acc += __shfl_down(acc, off, 64);
  if (f == 0) out[m] = 1.f / (1.f + expf(-(acc + b2[0])));
}

extern "C" void kernel_launch(void* const* d_in, const int* in_sizes, int n_in,
                              void* d_out, int out_size, void* d_ws,
                              size_t ws_size, hipStream_t stream) {
  const float* image = (const float*)d_in[0];
  const float* c1w = (const float*)d_in[1];
  const float* bn1g = (const float*)d_in[3];
  const float* bn1b = (const float*)d_in[4];
  const float* c2w = (const float*)d_in[5];
  const float* bn2g = (const float*)d_in[7];
  const float* bn2b = (const float*)d_in[8];
  const float* f1w = (const float*)d_in[9];
  const float* bn3g = (const float*)d_in[11];
  const float* bn3b = (const float*)d_in[12];
  const float* f2w = (const float*)d_in[13];
  const float* f2b = (const float*)d_in[14];
  float* ws = (float*)d_ws;

  // Workspace (floats). Region A [0, 5,225,472) = layT, dead after conv1:
  //   x2raw (2,359,296) @0, xT (2,359,296) @2,359,296, wT2 (51,200) @4,718,592.
  // Region B [5,225,472, 10,763,264) = x1raw (BN'd in place), dead after
  //   conv2: fc1part (128*32768 = 4,194,304) aliases it.
  float* layT = ws;
  float* x2raw = ws;
  float* xT = ws + 2359296;
  float* wT2 = ws + 4718592;
  float* x1raw = ws + 5225472;
  float* fc1part = ws + 5225472;
  float* fc1o = ws + 10763264;   // 32,768
  float* st = ws + 10796032;     // 192 (atomic sums, zeroed)
  float* bn1sum = st, *bn1sq = st + 32, *bn2sum = st + 64, *bn2sq = st + 128;
  float* coef = ws + 10796224;   // 1,216
  float* sc1 = coef, *sh1 = coef + 32;
  float* sc2 = coef + 64, *sh2 = coef + 128;
  float* sc3 = coef + 192, *sh3 = coef + 704;
  float* wT1 = ws + 10797440;    // 5,600

  hipMemsetAsync(st, 0, 192 * sizeof(float), stream);

  wprep1_kernel<<<22, 256, 0, stream>>>(c1w, wT1);
  layout_kernel<<<dim3(108, 64), 128, 0, stream>>>(image, layT);
  conv1_kernel<<<dim3(52, 64), 64, 0, stream>>>(layT, wT1, x1raw);
  wprep2_kernel<<<200, 256, 0, stream>>>(c2w, wT2);  // layT dead now
  stats_kernel<<<2048, 256, 0, stream>>>(x1raw, 2704, 32, bn1sum, bn1sq);
  bn_finalize_kernel<<<1, 64, 0, stream>>>(bn1sum, bn1sq, bn1g, bn1b,
                                           1.f / 173056.f, 32, sc1, sh1);
  bnapply1_kernel<<<5408, 256, 0, stream>>>(x1raw, sc1, sh1);
  conv2_kernel<<<dim3(24, 64), 256, 0, stream>>>(x1raw, wT2, x2raw);
  stats_kernel<<<4096, 256, 0, stream>>>(x2raw, 576, 64, bn2sum, bn2sq);
  bn_finalize_kernel<<<1, 64, 0, stream>>>(bn2sum, bn2sq, bn2g, bn2b,
                                           1.f / 36864.f, 64, sc2, sh2);
  transpose_bn2_kernel<<<576, 256, 0, stream>>>(x2raw, sc2, sh2, xT);
  fc1_kernel<<<dim3(128, 8), 128, 0, stream>>>(xT, f1w, fc1part);
  fc1_reduce_kernel<<<128, 256, 0, stream>>>(fc1part, fc1o);
  bn3_kernel<<<8, 64, 0, stream>>>(fc1o, bn3g, bn3b, sc3, sh3);
  fc2_kernel<<<64, 64, 0, stream>>>(fc1o, sc3, sh3, f2w, f2b, (float*)d_out);
}

// Round 4
// 297.135 us; speedup vs baseline: 2.5456x; 1.3081x over previous
//
#include <hip/hip_runtime.h>
#include <hip/hip_bf16.h>

// Discriminator pipeline. R4: conv1/conv2/fc1 on bf16 MFMA (16x16x32), fp32
// accumulate. Activations NHWC bf16 so conv A-fragments are contiguous 16B
// global loads (no im2col / no LDS in conv kernels). Weights pre-transposed
// to [n][k]-contiguous bf16 tables (L1-resident). BN stats in fp32 from the
// fp32 NHWC conv outputs. conv/fc biases absorbed by the following BN.
//
// MFMA convention (verified m89/m91/m97): D = mfma(a,b,c) computes
// D[m][n] = sum_k A[m][k]*B[n][k]; a: lane(f=m&15,q) elem j = A[f][q*8+j];
// b: lane(f=n,q) elem j = B[f][q*8+j]; d: lane l reg r = D[(l>>4)*4+r][l&15].

typedef unsigned short u16;
typedef __attribute__((ext_vector_type(8))) short bf8_t;
typedef __attribute__((ext_vector_type(4))) float f4_t;
#define MFMA16(a, b, c) __builtin_amdgcn_mfma_f32_16x16x32_bf16(a, b, c, 0, 0, 0)

#define LEAKY(v) (fmaxf((v), 0.2f * (v)))
#define CLIP01(v) fminf(fmaxf((v), 0.0f), 1.0f)

__device__ inline unsigned f2bf(float f) {  // RNE fp32->bf16 (low 16 bits)
  unsigned u = __float_as_uint(f);
  return (u + 0x7FFFu + ((u >> 16) & 1u)) >> 16;
}

constexpr int HW = 108;
constexpr int NOBJ = 16;
constexpr int NCLS = 7;

// ------------------------------------------------- layout_bbox -> NHWC8 bf16
// lay8[b][h][w][8]: ch 0..6 = classes, ch 7 = 0 pad. grid (108,64), block 128.
__global__ __launch_bounds__(128) void layout_kernel(
    const float* __restrict__ image, u16* __restrict__ lay8) {
  int h = blockIdx.x, b = blockIdx.y;
  __shared__ float sIm[NOBJ * 11];
  int tid = threadIdx.x;
  for (int i = tid; i < NOBJ * 11; i += 128) sIm[i] = image[b * NOBJ * 11 + i];
  __syncthreads();
  int w = tid;
  if (w >= HW) return;
  float best[NCLS];
#pragma unroll
  for (int c = 0; c < NCLS; ++c) best[c] = 0.0f;
  float fw = (float)w, fh = (float)h;
  for (int o = 0; o < NOBJ; ++o) {
    const float* p = &sIm[o * 11];
    float xc = p[0] * 108.0f, yc = p[1] * 108.0f;
    float wd = p[2] * 108.0f, hd = p[3] * 108.0f;
    float x1 = xc - 0.5f * wd, x2 = xc + 0.5f * wd;
    float y1 = yc - 0.5f * hd, y2 = yc + 0.5f * hd;
    float x1d = fw - x1, x2d = x2 - fw;
    float y1d = fh - y1, y2d = y2 - fh;
    float yband = CLIP01(y1d) * CLIP01(y2d);
    float xband = CLIP01(x1d) * CLIP01(x2d);
    float x1l = fmaxf(1.0f - fabsf(x1d), 0.0f) * yband;
    float x2l = fmaxf(1.0f - fabsf(x2d), 0.0f) * yband;
    float y1l = fmaxf(1.0f - fabsf(y1d), 0.0f) * xband;
    float y2l = fmaxf(1.0f - fabsf(y2d), 0.0f) * xband;
    float xy = fmaxf(fmaxf(x1l, x2l), fmaxf(y1l, y2l));
#pragma unroll
    for (int c = 0; c < NCLS; ++c) best[c] = fmaxf(best[c], xy * p[4 + c]);
  }
  unsigned p0 = f2bf(best[0]) | (f2bf(best[1]) << 16);
  unsigned p1 = f2bf(best[2]) | (f2bf(best[3]) << 16);
  unsigned p2 = f2bf(best[4]) | (f2bf(best[5]) << 16);
  unsigned p3 = f2bf(best[6]);
  uint4 st = {p0, p1, p2, p3};
  ((uint4*)lay8)[b * 11664 + h * 108 + w] = st;
}

// ------------------------------------------------------------- weight preps
// wB1[co][k=224]: k = chunk*32 + tl*8 + ci; tap = chunk*4+tl; 0 if tap>=25||ci>=7
__global__ __launch_bounds__(256) void wprep1_kernel(
    const float* __restrict__ w1, u16* __restrict__ wB1) {
  int i = blockIdx.x * 256 + threadIdx.x;  // 7168
  int co = i / 224, k = i % 224;
  int chunk = k >> 5, kk = k & 31, tl = kk >> 3, ci = kk & 7;
  int tap = chunk * 4 + tl;
  unsigned v = 0;
  if (tap < 25 && ci < 7) v = f2bf(w1[co * 175 + ci * 25 + tap]);
  wB1[i] = (u16)v;
}
// wB2[tap][co][ci32] bf16
__global__ __launch_bounds__(256) void wprep2_kernel(
    const float* __restrict__ w2, u16* __restrict__ wB2) {
  int i = blockIdx.x * 256 + threadIdx.x;  // 51200
  int tap = i / 2048, r = i % 2048, co = r >> 5, ci = r & 31;
  wB2[i] = (u16)f2bf(w2[co * 800 + ci * 25 + tap]);
}

// --------------------------------------------------------------- conv1 MFMA
// grid (13 strips, 64 b), block 128 = 2 waves; wave = one n-tile (16 co),
// 13 m-tiles (208 pixels = 4 oh rows). K = 7 chunks of 32 (4 taps x 8 ch).
// out x1c NHWC fp32 [b][2704][32].
__global__ __launch_bounds__(128) void conv1_mfma(
    const u16* __restrict__ lay8, const u16* __restrict__ wB1,
    float* __restrict__ x1c) {
  int strip = blockIdx.x, b = blockIdx.y;
  int tid = threadIdx.x;
  int lane = tid & 63, wv = tid >> 6;
  int f = lane & 15, q = lane >> 4;
  int co = wv * 16 + f;
  // per-lane pixel bases for the 13 m-tiles (a-frag side: m = 16t+f)
  int pbase[13];
#pragma unroll
  for (int t = 0; t < 13; ++t) {
    int P = strip * 208 + t * 16 + f;
    int oh = P / 52, ow = P - oh * 52;
    pbase[t] = (oh * 2 * 108 + ow * 2) * 8;
  }
  const u16* lb = lay8 + (size_t)b * 93312;
  f4_t acc[13];
#pragma unroll
  for (int t = 0; t < 13; ++t) acc[t] = {0.f, 0.f, 0.f, 0.f};
#pragma unroll
  for (int chunk = 0; chunk < 7; ++chunk) {
    int tap = chunk * 4 + q;
    tap = tap > 24 ? 24 : tap;  // dummy taps have zero weights
    int kh = tap / 5, kw = tap - kh * 5;
    int toff = (kh * 108 + kw) * 8;
    bf8_t bf = *(const bf8_t*)&wB1[co * 224 + chunk * 32 + q * 8];
    bf8_t af[13];
#pragma unroll
    for (int t = 0; t < 13; ++t) af[t] = *(const bf8_t*)&lb[pbase[t] + toff];
#pragma unroll
    for (int t = 0; t < 13; ++t) acc[t] = MFMA16(af[t], bf, acc[t]);
  }
  float* ob = x1c + (size_t)b * 2704 * 32;
#pragma unroll
  for (int t = 0; t < 13; ++t) {
#pragma unroll
    for (int r = 0; r < 4; ++r) {
      int P = strip * 208 + t * 16 + q * 4 + r;
      ob[P * 32 + co] = acc[t][r];
    }
  }
}

// ------------------------------------------- per-channel BN stats over NHWC
// src [rows][C], C power of 2. 256 rows per block.
__global__ __launch_bounds__(256) void stats_c_kernel(
    const float* __restrict__ src, int C, int logC,
    float* __restrict__ sumP, float* __restrict__ sqP) {
  int t = threadIdx.x;
  int c = t & (C - 1);
  int rl = t >> logC;
  int rpi = 256 >> logC;
  const float* p = src + (size_t)blockIdx.x * 256 * C;
  float s = 0.f, q = 0.f;
  for (int it = 0; it < C; ++it) {
    float v = p[(it * rpi + rl) * C + c];
    s += v;
    q += v * v;
  }
  __shared__ float ls[256], lq[256];
  ls[t] = s;
  lq[t] = q;
  __syncthreads();
  if (t < C) {
    float ss = 0.f, qq = 0.f;
    for (int j = t; j < 256; j += C) { ss += ls[j]; qq += lq[j]; }
    atomicAdd(&sumP[t], ss);
    atomicAdd(&sqP[t], qq);
  }
}

__global__ void bn_finalize_kernel(
    const float* __restrict__ sum, const float* __restrict__ sumsq,
    const float* __restrict__ g, const float* __restrict__ bb, float invN,
    int C, float* __restrict__ scale, float* __restrict__ shift) {
  int c = threadIdx.x;
  if (c < C) {
    float mean = sum[c] * invN;
    float var = sumsq[c] * invN - mean * mean;
    float sc = g[c] * rsqrtf(var + 1e-5f);
    scale[c] = sc;
    shift[c] = bb[c] - mean * sc;
  }
}

// ---------------------- BN1+leaky: x1c NHWC fp32 -> x1b NHWC bf16 (8/thread)
__global__ __launch_bounds__(256) void bnapply1_kernel(
    const float* __restrict__ x1c, const float* __restrict__ sc,
    const float* __restrict__ sh, u16* __restrict__ x1b) {
  int idx = blockIdx.x * 256 + threadIdx.x;  // 692,224
  int base = idx * 8, c0 = base & 31;
  float4 v0 = *(const float4*)&x1c[base];
  float4 v1 = *(const float4*)&x1c[base + 4];
  float o[8] = {v0.x, v0.y, v0.z, v0.w, v1.x, v1.y, v1.z, v1.w};
  unsigned out[4];
#pragma unroll
  for (int j = 0; j < 4; ++j) {
    float a = LEAKY(fmaf(o[2 * j], sc[c0 + 2 * j], sh[c0 + 2 * j]));
    float bq = LEAKY(fmaf(o[2 * j + 1], sc[c0 + 2 * j + 1], sh[c0 + 2 * j + 1]));
    out[j] = f2bf(a) | (f2bf(bq) << 16);
  }
  uint4 st = {out[0], out[1], out[2], out[3]};
  *(uint4*)&x1b[base] = st;
}

// --------------------------------------------------------------- conv2 MFMA
// grid (6 strips, 64 b), block 256 = 4 waves. Wave: m-tiles (wv>>1)*3..+2,
// n-tiles (wv&1)*2..+1. 25 taps, K=32=ci each, accumulate in regs.
// LDS-free: a-frags 16B contiguous from x1b NHWC; b-frags from wB2 (L1).
// out x2c NHWC fp32 [b][576][64].
__global__ __launch_bounds__(256) void conv2_mfma(
    const u16* __restrict__ x1b, const u16* __restrict__ wB2,
    float* __restrict__ x2c) {
  int strip = blockIdx.x, b = blockIdx.y;
  int tid = threadIdx.x;
  int lane = tid & 63, wv = tid >> 6;
  int f = lane & 15, q = lane >> 4;
  int mbase = (wv >> 1) * 3, nbase = (wv & 1) * 2;
  int pbase[3];
#pragma unroll
  for (int t = 0; t < 3; ++t) {
    int P = strip * 96 + (mbase + t) * 16 + f;
    int oh = P / 24, ow = P - oh * 24;
    pbase[t] = (oh * 2 * 52 + ow * 2) * 32 + q * 8;
  }
  const u16* xb = x1b + (size_t)b * 86528;
  f4_t acc[3][2];
#pragma unroll
  for (int t = 0; t < 3; ++t)
#pragma unroll
    for (int n = 0; n < 2; ++n) acc[t][n] = {0.f, 0.f, 0.f, 0.f};
#pragma unroll
  for (int tap = 0; tap < 25; ++tap) {
    int kh = tap / 5, kw = tap - kh * 5;
    int toff = (kh * 52 + kw) * 32;
    bf8_t bfr[2];
#pragma unroll
    for (int n = 0; n < 2; ++n)
      bfr[n] = *(const bf8_t*)&wB2[tap * 2048 + ((nbase + n) * 16 + f) * 32 + q * 8];
    bf8_t afr[3];
#pragma unroll
    for (int t = 0; t < 3; ++t) afr[t] = *(const bf8_t*)&xb[pbase[t] + toff];
#pragma unroll
    for (int t = 0; t < 3; ++t)
#pragma unroll
      for (int n = 0; n < 2; ++n) acc[t][n] = MFMA16(afr[t], bfr[n], acc[t][n]);
  }
  float* ob = x2c + (size_t)b * 576 * 64;
#pragma unroll
  for (int t = 0; t < 3; ++t)
#pragma unroll
    for (int n = 0; n < 2; ++n)
#pragma unroll
      for (int r = 0; r < 4; ++r) {
        int P = strip * 96 + (mbase + t) * 16 + q * 4 + r;
        ob[P * 64 + (nbase + n) * 16 + f] = acc[t][n][r];
      }
}

// -------------- BN2+leaky + NHWC->NCHW: x2c [b][576][64] -> xB bf16 [b][64*576]
__global__ __launch_bounds__(256) void bnapply2t_kernel(
    const float* __restrict__ x2c, const float* __restrict__ sc2,
    const float* __restrict__ sh2, u16* __restrict__ xB) {
  int hw0 = blockIdx.x * 64, b = blockIdx.y;
  __shared__ float tile[64 * 65];
  int t = threadIdx.x;
  int c = t & 63, hl4 = t >> 6;
  float s = sc2[c], h = sh2[c];
#pragma unroll
  for (int it = 0; it < 16; ++it) {
    int hl = it * 4 + hl4;
    float v = x2c[((size_t)b * 576 + hw0 + hl) * 64 + c];
    tile[hl * 65 + c] = LEAKY(fmaf(v, s, h));
  }
  __syncthreads();
  int hw = t & 63, cl4 = t >> 6;
#pragma unroll
  for (int it = 0; it < 16; ++it) {
    int cc = it * 4 + cl4;
    xB[(size_t)b * 36864 + cc * 576 + hw0 + hw] = (u16)f2bf(tile[hw * 65 + cc]);
  }
}

// ----------------------------------------------------------------- fc1 MFMA
// part[ks][64][512] += A(bf16)[64][1024-chunk] x W(fp32->bf16)[512][k].
// grid (36 ks, 8 nb), block 256 = 4 waves; wave -> n-sub 16. A staged in LDS.
__global__ __launch_bounds__(256) void fc1_mfma(
    const u16* __restrict__ xB, const float* __restrict__ wgt,
    float* __restrict__ part) {
  int ks = blockIdx.x, nb = blockIdx.y;
  int tid = threadIdx.x;
  int lane = tid & 63, wv = tid >> 6;
  int f = lane & 15, q = lane >> 4;
  int n0 = nb * 64 + wv * 16;
  __shared__ u16 sA[64 * 32];
  f4_t acc[4];
#pragma unroll
  for (int m = 0; m < 4; ++m) acc[m] = {0.f, 0.f, 0.f, 0.f};
  int kbase = ks * 1024;
  for (int kt = 0; kt < 32; ++kt) {
    int k0 = kbase + kt * 32;
    __syncthreads();
    *(uint4*)&sA[(tid >> 2) * 32 + (tid & 3) * 8] =
        *(const uint4*)&xB[(size_t)(tid >> 2) * 36864 + k0 + (tid & 3) * 8];
    __syncthreads();
    const float* wp = wgt + (size_t)(n0 + f) * 36864 + k0 + q * 8;
    float4 wa = *(const float4*)wp;
    float4 wb = *(const float4*)(wp + 4);
    union { bf8_t v; u16 u[8]; } bu;
    bu.u[0] = (u16)f2bf(wa.x); bu.u[1] = (u16)f2bf(wa.y);
    bu.u[2] = (u16)f2bf(wa.z); bu.u[3] = (u16)f2bf(wa.w);
    bu.u[4] = (u16)f2bf(wb.x); bu.u[5] = (u16)f2bf(wb.y);
    bu.u[6] = (u16)f2bf(wb.z); bu.u[7] = (u16)f2bf(wb.w);
    bf8_t afr[4];
#pragma unroll
    for (int m = 0; m < 4; ++m)
      afr[m] = *(const bf8_t*)&sA[(m * 16 + f) * 32 + q * 8];
#pragma unroll
    for (int m = 0; m < 4; ++m) acc[m] = MFMA16(afr[m], bu.v, acc[m]);
  }
  float* pp = part + (size_t)ks * 32768;
#pragma unroll
  for (int m = 0; m < 4; ++m)
#pragma unroll
    for (int r = 0; r < 4; ++r)
      pp[(m * 16 + q * 4 + r) * 512 + n0 + f] = acc[m][r];
}

// sum the 36 split-K partials
__global__ __launch_bounds__(256) void fc1_reduce_kernel(
    const float* __restrict__ part, float* __restrict__ out) {
  int i = blockIdx.x * 256 + threadIdx.x;  // 0..32767
  float s = 0.f;
#pragma unroll 4
  for (int ks = 0; ks < 36; ++ks) s += part[(size_t)ks * 32768 + i];
  out[i] = s;
}

// ------------------------------------------------------- BN3 (per feature)
__global__ __launch_bounds__(64) void bn3_kernel(
    const float* __restrict__ fc1o, const float* __restrict__ g,
    const float* __restrict__ bb, float* __restrict__ scale,
    float* __restrict__ shift) {
  int f = blockIdx.x * 64 + threadIdx.x;
  float s = 0.f, q = 0.f;
  for (int m = 0; m < 64; ++m) {
    float v = fc1o[m * 512 + f];
    s += v;
    q += v * v;
  }
  float mean = s * (1.f / 64.f);
  float var = q * (1.f / 64.f) - mean * mean;
  float sc = g[f] * rsqrtf(var + 1e-5f);
  scale[f] = sc;
  shift[f] = bb[f] - mean * sc;
}

// ------------------------------------------- BN3-apply + leaky + fc2 + sigmoid
__global__ __launch_bounds__(64) void fc2_kernel(
    const float* __restrict__ fc1o, const float* __restrict__ sc,
    const float* __restrict__ sh, const float* __restrict__ w2,
    const float* __restrict__ b2, float* __restrict__ out) {
  int m = blockIdx.x;
  int f = threadIdx.x;
  float acc = 0.f;
#pragma unroll
  for (int j = 0; j < 8; ++j) {
    int ff = f + j * 64;
    float v = fc1o[m * 512 + ff] * sc[ff] + sh[ff];
    v = LEAKY(v);
    acc += v * w2[ff];
  }
  for (int off = 32; off; off >>= 1) acc += __shfl_down(acc, off, 64);
  if (f == 0) out[m] = 1.f / (1.f + expf(-(acc + b2[0])));
}

extern "C" void kernel_launch(void* const* d_in, const int* in_sizes, int n_in,
                              void* d_out, int out_size, void* d_ws,
                              size_t ws_size, hipStream_t stream) {
  const float* image = (const float*)d_in[0];
  const float* c1w = (const float*)d_in[1];
  const float* bn1g = (const float*)d_in[3];
  const float* bn1b = (const float*)d_in[4];
  const float* c2w = (const float*)d_in[5];
  const float* bn2g = (const float*)d_in[7];
  const float* bn2b = (const float*)d_in[8];
  const float* f1w = (const float*)d_in[9];
  const float* bn3g = (const float*)d_in[11];
  const float* bn3b = (const float*)d_in[12];
  const float* f2w = (const float*)d_in[13];
  const float* f2b = (const float*)d_in[14];
  float* ws = (float*)d_ws;

  // Workspace (float units), aliased by lifetime:
  //  [0, 2,985,984)        lay8 (u16 x 5,971,968); later x1b (u16 x 5,537,792)
  //  [2,985,984, 8,523,776) x1c fp32 (5,537,792); later x2c fp32 (2,359,296)
  //      @5,345,280 xB (u16 x 2,359,296 = 1,179,648 f)
  //      @6,524,928 fc1part (36*32768 = 1,179,648 f)
  //  [8,523,776 ...) fc1o, stats, coef, wB1, wB2   (total 34.3 MB)
  u16* lay8 = (u16*)ws;
  u16* x1b = (u16*)ws;
  float* x1c = ws + 2985984;
  float* x2c = ws + 2985984;
  u16* xB = (u16*)(ws + 5345280);
  float* fc1part = ws + 6524928;
  float* fc1o = ws + 8523776;
  float* st = ws + 8556544;  // 192, zeroed
  float* bn1sum = st, *bn1sq = st + 32, *bn2sum = st + 64, *bn2sq = st + 128;
  float* coef = ws + 8556736;
  float* sc1 = coef, *sh1 = coef + 32;
  float* sc2 = coef + 64, *sh2 = coef + 128;
  float* sc3 = coef + 192, *sh3 = coef + 704;
  u16* wB1 = (u16*)(ws + 8557952);
  u16* wB2 = (u16*)(ws + 8561536);

  hipMemsetAsync(st, 0, 192 * sizeof(float), stream);

  wprep1_kernel<<<28, 256, 0, stream>>>(c1w, wB1);
  wprep2_kernel<<<200, 256, 0, stream>>>(c2w, wB2);
  layout_kernel<<<dim3(108, 64), 128, 0, stream>>>(image, lay8);
  conv1_mfma<<<dim3(13, 64), 128, 0, stream>>>(lay8, wB1, x1c);
  stats_c_kernel<<<676, 256, 0, stream>>>(x1c, 32, 5, bn1sum, bn1sq);
  bn_finalize_kernel<<<1, 64, 0, stream>>>(bn1sum, bn1sq, bn1g, bn1b,
                                           1.f / 173056.f, 32, sc1, sh1);
  bnapply1_kernel<<<2704, 256, 0, stream>>>(x1c, sc1, sh1, x1b);  // lay8 dead
  conv2_mfma<<<dim3(6, 64), 256, 0, stream>>>(x1b, wB2, x2c);     // x1c dead
  stats_c_kernel<<<144, 256, 0, stream>>>(x2c, 64, 6, bn2sum, bn2sq);
  bn_finalize_kernel<<<1, 64, 0, stream>>>(bn2sum, bn2sq, bn2g, bn2b,
                                           1.f / 36864.f, 64, sc2, sh2);
  bnapply2t_kernel<<<dim3(9, 64), 256, 0, stream>>>(x2c, sc2, sh2, xB);
  fc1_mfma<<<dim3(36, 8), 256, 0, stream>>>(xB, f1w, fc1part);
  fc1_reduce_kernel<<<128, 256, 0, stream>>>(fc1part, fc1o);
  bn3_kernel<<<8, 64, 0, stream>>>(fc1o, bn3g, bn3b, sc3, sh3);
  fc2_kernel<<<64, 64, 0, stream>>>(fc1o, sc3, sh3, f2w, f2b, (float*)d_out);
}

// Round 5
// 256.375 us; speedup vs baseline: 2.9503x; 1.1590x over previous
//
#include <hip/hip_runtime.h>
#include <hip/hip_bf16.h>

// Discriminator pipeline. R5: fc1 restructured (A staged once per block,
// barrier-free K loop, 72-way split-K, padded LDS); BN1/BN2 stats fused into
// conv epilogues (register shfl-reduce + per-block atomics); conv1 emits bf16;
// wpreps merged. conv/fc biases absorbed by the following BN.
//
// MFMA convention (verified m89/m91): D = mfma(a,b,c): D[m][n] = sum_k
// A[m][k]*B[n][k]; a: lane(f=m&15,q=lane>>4) elem j = A[f][q*8+j]; b same with
// f=n; d: lane l reg r = D[(l>>4)*4+r][l&15].

typedef unsigned short u16;
typedef __attribute__((ext_vector_type(8))) short bf8_t;
typedef __attribute__((ext_vector_type(4))) float f4_t;
#define MFMA16(a, b, c) __builtin_amdgcn_mfma_f32_16x16x32_bf16(a, b, c, 0, 0, 0)

#define LEAKY(v) (fmaxf((v), 0.2f * (v)))
#define CLIP01(v) fminf(fmaxf((v), 0.0f), 1.0f)

__device__ inline unsigned f2bf(float f) {  // RNE fp32->bf16 (low 16 bits)
  unsigned u = __float_as_uint(f);
  return (u + 0x7FFFu + ((u >> 16) & 1u)) >> 16;
}
__device__ inline float bf2f(unsigned u) {
  return __uint_as_float(u << 16);
}

constexpr int HW = 108;
constexpr int NOBJ = 16;
constexpr int NCLS = 7;

// ------------------------------------------------- layout_bbox -> NHWC8 bf16
__global__ __launch_bounds__(128) void layout_kernel(
    const float* __restrict__ image, u16* __restrict__ lay8) {
  int h = blockIdx.x, b = blockIdx.y;
  __shared__ float sIm[NOBJ * 11];
  int tid = threadIdx.x;
  for (int i = tid; i < NOBJ * 11; i += 128) sIm[i] = image[b * NOBJ * 11 + i];
  __syncthreads();
  int w = tid;
  if (w >= HW) return;
  float best[NCLS];
#pragma unroll
  for (int c = 0; c < NCLS; ++c) best[c] = 0.0f;
  float fw = (float)w, fh = (float)h;
  for (int o = 0; o < NOBJ; ++o) {
    const float* p = &sIm[o * 11];
    float xc = p[0] * 108.0f, yc = p[1] * 108.0f;
    float wd = p[2] * 108.0f, hd = p[3] * 108.0f;
    float x1 = xc - 0.5f * wd, x2 = xc + 0.5f * wd;
    float y1 = yc - 0.5f * hd, y2 = yc + 0.5f * hd;
    float x1d = fw - x1, x2d = x2 - fw;
    float y1d = fh - y1, y2d = y2 - fh;
    float yband = CLIP01(y1d) * CLIP01(y2d);
    float xband = CLIP01(x1d) * CLIP01(x2d);
    float x1l = fmaxf(1.0f - fabsf(x1d), 0.0f) * yband;
    float x2l = fmaxf(1.0f - fabsf(x2d), 0.0f) * yband;
    float y1l = fmaxf(1.0f - fabsf(y1d), 0.0f) * xband;
    float y2l = fmaxf(1.0f - fabsf(y2d), 0.0f) * xband;
    float xy = fmaxf(fmaxf(x1l, x2l), fmaxf(y1l, y2l));
#pragma unroll
    for (int c = 0; c < NCLS; ++c) best[c] = fmaxf(best[c], xy * p[4 + c]);
  }
  unsigned p0 = f2bf(best[0]) | (f2bf(best[1]) << 16);
  unsigned p1 = f2bf(best[2]) | (f2bf(best[3]) << 16);
  unsigned p2 = f2bf(best[4]) | (f2bf(best[5]) << 16);
  unsigned p3 = f2bf(best[6]);
  uint4 st = {p0, p1, p2, p3};
  ((uint4*)lay8)[b * 11664 + h * 108 + w] = st;
}

// ------------------------------------------------------- merged weight prep
// wB1[co][k=224]: k = chunk*32 + tl*8 + ci; tap=chunk*4+tl; 0 pad beyond.
// wB2[tap][co][ci32].
__global__ __launch_bounds__(256) void wprep_kernel(
    const float* __restrict__ w1, const float* __restrict__ w2,
    u16* __restrict__ wB1, u16* __restrict__ wB2) {
  int i = blockIdx.x * 256 + threadIdx.x;
  if (i < 7168) {
    int co = i / 224, k = i % 224;
    int chunk = k >> 5, kk = k & 31, tl = kk >> 3, ci = kk & 7;
    int tap = chunk * 4 + tl;
    unsigned v = 0;
    if (tap < 25 && ci < 7) v = f2bf(w1[co * 175 + ci * 25 + tap]);
    wB1[i] = (u16)v;
  } else {
    int j = i - 7168;  // < 51200
    int tap = j / 2048, r = j % 2048, co = r >> 5, ci = r & 31;
    wB2[j] = (u16)f2bf(w2[co * 800 + ci * 25 + tap]);
  }
}

// --------------------------------------------------------------- conv1 MFMA
// grid (13, 64), block 128 = 2 waves; wave = 16 co, 13 m-tiles. Output bf16
// NHWC x1r[b][2704][32]; BN1 stats fused (exact fp32 accs).
__global__ __launch_bounds__(128) void conv1_mfma(
    const u16* __restrict__ lay8, const u16* __restrict__ wB1,
    u16* __restrict__ x1r, float* __restrict__ bn1sum,
    float* __restrict__ bn1sq) {
  int strip = blockIdx.x, b = blockIdx.y;
  int tid = threadIdx.x;
  int lane = tid & 63, wv = tid >> 6;
  int f = lane & 15, q = lane >> 4;
  int co = wv * 16 + f;
  int pbase[13];
#pragma unroll
  for (int t = 0; t < 13; ++t) {
    int P = strip * 208 + t * 16 + f;
    int oh = P / 52, ow = P - oh * 52;
    pbase[t] = (oh * 2 * 108 + ow * 2) * 8;
  }
  const u16* lb = lay8 + (size_t)b * 93312;
  f4_t acc[13];
#pragma unroll
  for (int t = 0; t < 13; ++t) acc[t] = {0.f, 0.f, 0.f, 0.f};
#pragma unroll
  for (int chunk = 0; chunk < 7; ++chunk) {
    int tap = chunk * 4 + q;
    tap = tap > 24 ? 24 : tap;  // dup taps carry zero weights
    int kh = tap / 5, kw = tap - kh * 5;
    int toff = (kh * 108 + kw) * 8;
    bf8_t bf = *(const bf8_t*)&wB1[co * 224 + chunk * 32 + q * 8];
    bf8_t af[13];
#pragma unroll
    for (int t = 0; t < 13; ++t) af[t] = *(const bf8_t*)&lb[pbase[t] + toff];
#pragma unroll
    for (int t = 0; t < 13; ++t) acc[t] = MFMA16(af[t], bf, acc[t]);
  }
  u16* ob = x1r + (size_t)b * 86528;
  float s = 0.f, sq = 0.f;
#pragma unroll
  for (int t = 0; t < 13; ++t) {
#pragma unroll
    for (int r = 0; r < 4; ++r) {
      float v = acc[t][r];
      s += v;
      sq += v * v;
      int P = strip * 208 + t * 16 + q * 4 + r;
      ob[P * 32 + co] = (u16)f2bf(v);
    }
  }
  s += __shfl_xor(s, 16);
  s += __shfl_xor(s, 32);
  sq += __shfl_xor(sq, 16);
  sq += __shfl_xor(sq, 32);
  if (lane < 16) {
    atomicAdd(&bn1sum[co], s);
    atomicAdd(&bn1sq[co], sq);
  }
}

__global__ void bn_finalize_kernel(
    const float* __restrict__ sum, const float* __restrict__ sumsq,
    const float* __restrict__ g, const float* __restrict__ bb, float invN,
    int C, float* __restrict__ scale, float* __restrict__ shift) {
  int c = threadIdx.x;
  if (c < C) {
    float mean = sum[c] * invN;
    float var = sumsq[c] * invN - mean * mean;
    float sc = g[c] * rsqrtf(var + 1e-5f);
    scale[c] = sc;
    shift[c] = bb[c] - mean * sc;
  }
}

// ------------- BN1+leaky: x1r NHWC bf16 -> x1b NHWC bf16 (8 elems / thread)
__global__ __launch_bounds__(256) void bnapply1_kernel(
    const u16* __restrict__ x1r, const float* __restrict__ sc,
    const float* __restrict__ sh, u16* __restrict__ x1b) {
  int idx = blockIdx.x * 256 + threadIdx.x;  // 692,224
  int base = idx * 8, c0 = base & 31;
  uint4 in = *(const uint4*)&x1r[base];
  unsigned w[4] = {in.x, in.y, in.z, in.w};
  unsigned out[4];
#pragma unroll
  for (int j = 0; j < 4; ++j) {
    float a = bf2f(w[j] & 0xffffu);
    float bq = bf2f(w[j] >> 16);
    a = LEAKY(fmaf(a, sc[c0 + 2 * j], sh[c0 + 2 * j]));
    bq = LEAKY(fmaf(bq, sc[c0 + 2 * j + 1], sh[c0 + 2 * j + 1]));
    out[j] = f2bf(a) | (f2bf(bq) << 16);
  }
  uint4 st = {out[0], out[1], out[2], out[3]};
  *(uint4*)&x1b[base] = st;
}

// --------------------------------------------------------------- conv2 MFMA
// grid (6, 64), block 256 = 4 waves; wave: 3 m-tiles, 2 n-tiles. LDS-free.
// BN2 stats fused. out x2c NHWC fp32 [b][576][64].
__global__ __launch_bounds__(256) void conv2_mfma(
    const u16* __restrict__ x1b, const u16* __restrict__ wB2,
    float* __restrict__ x2c, float* __restrict__ bn2sum,
    float* __restrict__ bn2sq) {
  int strip = blockIdx.x, b = blockIdx.y;
  int tid = threadIdx.x;
  int lane = tid & 63, wv = tid >> 6;
  int f = lane & 15, q = lane >> 4;
  int mbase = (wv >> 1) * 3, nbase = (wv & 1) * 2;
  int pbase[3];
#pragma unroll
  for (int t = 0; t < 3; ++t) {
    int P = strip * 96 + (mbase + t) * 16 + f;
    int oh = P / 24, ow = P - oh * 24;
    pbase[t] = (oh * 2 * 52 + ow * 2) * 32 + q * 8;
  }
  const u16* xb = x1b + (size_t)b * 86528;
  f4_t acc[3][2];
#pragma unroll
  for (int t = 0; t < 3; ++t)
#pragma unroll
    for (int n = 0; n < 2; ++n) acc[t][n] = {0.f, 0.f, 0.f, 0.f};
#pragma unroll
  for (int tap = 0; tap < 25; ++tap) {
    int kh = tap / 5, kw = tap - kh * 5;
    int toff = (kh * 52 + kw) * 32;
    bf8_t bfr[2];
#pragma unroll
    for (int n = 0; n < 2; ++n)
      bfr[n] =
          *(const bf8_t*)&wB2[tap * 2048 + ((nbase + n) * 16 + f) * 32 + q * 8];
    bf8_t afr[3];
#pragma unroll
    for (int t = 0; t < 3; ++t) afr[t] = *(const bf8_t*)&xb[pbase[t] + toff];
#pragma unroll
    for (int t = 0; t < 3; ++t)
#pragma unroll
      for (int n = 0; n < 2; ++n) acc[t][n] = MFMA16(afr[t], bfr[n], acc[t][n]);
  }
  float* ob = x2c + (size_t)b * 576 * 64;
  float s[2] = {0.f, 0.f}, sq[2] = {0.f, 0.f};
#pragma unroll
  for (int t = 0; t < 3; ++t)
#pragma unroll
    for (int n = 0; n < 2; ++n)
#pragma unroll
      for (int r = 0; r < 4; ++r) {
        float v = acc[t][n][r];
        s[n] += v;
        sq[n] += v * v;
        int P = strip * 96 + (mbase + t) * 16 + q * 4 + r;
        ob[P * 64 + (nbase + n) * 16 + f] = v;
      }
#pragma unroll
  for (int n = 0; n < 2; ++n) {
    s[n] += __shfl_xor(s[n], 16);
    s[n] += __shfl_xor(s[n], 32);
    sq[n] += __shfl_xor(sq[n], 16);
    sq[n] += __shfl_xor(sq[n], 32);
  }
  if (lane < 16) {
#pragma unroll
    for (int n = 0; n < 2; ++n) {
      int c = (nbase + n) * 16 + f;
      atomicAdd(&bn2sum[c], s[n]);
      atomicAdd(&bn2sq[c], sq[n]);
    }
  }
}

// ------------- BN2+leaky + NHWC->NCHW: x2c [b][576][64] -> xB bf16 [b][64*576]
__global__ __launch_bounds__(256) void bnapply2t_kernel(
    const float* __restrict__ x2c, const float* __restrict__ sc2,
    const float* __restrict__ sh2, u16* __restrict__ xB) {
  int hw0 = blockIdx.x * 64, b = blockIdx.y;
  __shared__ float tile[64 * 65];
  int t = threadIdx.x;
  int c = t & 63, hl4 = t >> 6;
  float s = sc2[c], h = sh2[c];
#pragma unroll
  for (int it = 0; it < 16; ++it) {
    int hl = it * 4 + hl4;
    float v = x2c[((size_t)b * 576 + hw0 + hl) * 64 + c];
    tile[hl * 65 + c] = LEAKY(fmaf(v, s, h));
  }
  __syncthreads();
  int hw = t & 63, cl4 = t >> 6;
#pragma unroll
  for (int it = 0; it < 16; ++it) {
    int cc = it * 4 + cl4;
    xB[(size_t)b * 36864 + cc * 576 + hw0 + hw] = (u16)f2bf(tile[hw * 65 + cc]);
  }
}

// ----------------------------------------------------------------- fc1 MFMA
// part[ks][64][512]: A bf16 [64][36864] x W fp32[512][36864] (cvt in-flight).
// grid (72 ks, 8 nb), block 256 = 4 waves; k-range 512/block. A staged ONCE
// in LDS (row pad +8 u16 -> 2-way bank alias only); K loop barrier-free.
__global__ __launch_bounds__(256) void fc1_mfma(
    const u16* __restrict__ xB, const float* __restrict__ wgt,
    float* __restrict__ part) {
  int ks = blockIdx.x, nb = blockIdx.y;
  int tid = threadIdx.x;
  int lane = tid & 63, wv = tid >> 6;
  int f = lane & 15, q = lane >> 4;
  int n0 = nb * 64 + wv * 16;
  int kbase = ks * 512;
  __shared__ u16 sA[64 * 520];
#pragma unroll
  for (int i = 0; i < 16; ++i) {
    int c = i * 256 + tid;            // 0..4095
    int row = c >> 6, col = c & 63;   // col in uint4 (8-u16) units
    *(uint4*)&sA[row * 520 + col * 8] =
        *(const uint4*)&xB[(size_t)row * 36864 + kbase + col * 8];
  }
  __syncthreads();
  f4_t acc[4];
#pragma unroll
  for (int m = 0; m < 4; ++m) acc[m] = {0.f, 0.f, 0.f, 0.f};
  const float* wrow = wgt + (size_t)(n0 + f) * 36864 + kbase + q * 8;
#pragma unroll 4
  for (int kt = 0; kt < 16; ++kt) {
    const float* wp = wrow + kt * 32;
    float4 wa = *(const float4*)wp;
    float4 wb = *(const float4*)(wp + 4);
    union { bf8_t v; u16 u[8]; } bu;
    bu.u[0] = (u16)f2bf(wa.x); bu.u[1] = (u16)f2bf(wa.y);
    bu.u[2] = (u16)f2bf(wa.z); bu.u[3] = (u16)f2bf(wa.w);
    bu.u[4] = (u16)f2bf(wb.x); bu.u[5] = (u16)f2bf(wb.y);
    bu.u[6] = (u16)f2bf(wb.z); bu.u[7] = (u16)f2bf(wb.w);
    bf8_t afr[4];
#pragma unroll
    for (int m = 0; m < 4; ++m)
      afr[m] = *(const bf8_t*)&sA[(m * 16 + f) * 520 + kt * 32 + q * 8];
#pragma unroll
    for (int m = 0; m < 4; ++m) acc[m] = MFMA16(afr[m], bu.v, acc[m]);
  }
  float* pp = part + (size_t)ks * 32768;
#pragma unroll
  for (int m = 0; m < 4; ++m)
#pragma unroll
    for (int r = 0; r < 4; ++r)
      pp[(m * 16 + q * 4 + r) * 512 + n0 + f] = acc[m][r];
}

// sum the 72 split-K partials
__global__ __launch_bounds__(256) void fc1_reduce_kernel(
    const float* __restrict__ part, float* __restrict__ out) {
  int i = blockIdx.x * 256 + threadIdx.x;  // 0..32767
  float s = 0.f;
#pragma unroll 8
  for (int ks = 0; ks < 72; ++ks) s += part[(size_t)ks * 32768 + i];
  out[i] = s;
}

// ------------------------------------------------------- BN3 (per feature)
__global__ __launch_bounds__(64) void bn3_kernel(
    const float* __restrict__ fc1o, const float* __restrict__ g,
    const float* __restrict__ bb, float* __restrict__ scale,
    float* __restrict__ shift) {
  int f = blockIdx.x * 64 + threadIdx.x;
  float s = 0.f, q = 0.f;
  for (int m = 0; m < 64; ++m) {
    float v = fc1o[m * 512 + f];
    s += v;
    q += v * v;
  }
  float mean = s * (1.f / 64.f);
  float var = q * (1.f / 64.f) - mean * mean;
  float sc = g[f] * rsqrtf(var + 1e-5f);
  scale[f] = sc;
  shift[f] = bb[f] - mean * sc;
}

// ------------------------------------------- BN3-apply + leaky + fc2 + sigmoid
__global__ __launch_bounds__(64) void fc2_kernel(
    const float* __restrict__ fc1o, const float* __restrict__ sc,
    const float* __restrict__ sh, const float* __restrict__ w2,
    const float* __restrict__ b2, float* __restrict__ out) {
  int m = blockIdx.x;
  int f = threadIdx.x;
  float acc = 0.f;
#pragma unroll
  for (int j = 0; j < 8; ++j) {
    int ff = f + j * 64;
    float v = fc1o[m * 512 + ff] * sc[ff] + sh[ff];
    v = LEAKY(v);
    acc += v * w2[ff];
  }
  for (int off = 32; off; off >>= 1) acc += __shfl_down(acc, off, 64);
  if (f == 0) out[m] = 1.f / (1.f + expf(-(acc + b2[0])));
}

extern "C" void kernel_launch(void* const* d_in, const int* in_sizes, int n_in,
                              void* d_out, int out_size, void* d_ws,
                              size_t ws_size, hipStream_t stream) {
  const float* image = (const float*)d_in[0];
  const float* c1w = (const float*)d_in[1];
  const float* bn1g = (const float*)d_in[3];
  const float* bn1b = (const float*)d_in[4];
  const float* c2w = (const float*)d_in[5];
  const float* bn2g = (const float*)d_in[7];
  const float* bn2b = (const float*)d_in[8];
  const float* f1w = (const float*)d_in[9];
  const float* bn3g = (const float*)d_in[11];
  const float* bn3b = (const float*)d_in[12];
  const float* f2w = (const float*)d_in[13];
  const float* f2b = (const float*)d_in[14];
  float* ws = (float*)d_ws;

  // Workspace (float units), aliased by lifetime:
  //  [0, 2,985,984)         lay8 u16; after conv1: x1b u16 (2,768,896 f)
  //  [2,985,984, 5,754,880) x1r u16 (conv1 out); after bnapply1:
  //                         x2c fp32 (2,359,296 f); after bnapply2t:
  //                         fc1part (72*32768 = 2,359,296 f)
  //  [5,345,280, 6,524,928) xB u16 (1,179,648 f)   [after x1r dead]
  //  [6,524,928 ...)        fc1o, stats, coef, wB1, wB2  (total ~26.4 MB)
  u16* lay8 = (u16*)ws;
  u16* x1b = (u16*)ws;
  u16* x1r = (u16*)(ws + 2985984);
  float* x2c = ws + 2985984;
  float* fc1part = ws + 2985984;
  u16* xB = (u16*)(ws + 5345280);
  float* fc1o = ws + 6524928;
  float* st = ws + 6557696;  // 192, zeroed
  float* bn1sum = st, *bn1sq = st + 32, *bn2sum = st + 64, *bn2sq = st + 128;
  float* coef = ws + 6557888;
  float* sc1 = coef, *sh1 = coef + 32;
  float* sc2 = coef + 64, *sh2 = coef + 128;
  float* sc3 = coef + 192, *sh3 = coef + 704;
  u16* wB1 = (u16*)(ws + 6559104);  // 7,168 u16
  u16* wB2 = (u16*)(ws + 6562688);  // 51,200 u16

  hipMemsetAsync(st, 0, 192 * sizeof(float), stream);

  wprep_kernel<<<228, 256, 0, stream>>>(c1w, c2w, wB1, wB2);
  layout_kernel<<<dim3(108, 64), 128, 0, stream>>>(image, lay8);
  conv1_mfma<<<dim3(13, 64), 128, 0, stream>>>(lay8, wB1, x1r, bn1sum, bn1sq);
  bn_finalize_kernel<<<1, 64, 0, stream>>>(bn1sum, bn1sq, bn1g, bn1b,
                                           1.f / 173056.f, 32, sc1, sh1);
  bnapply1_kernel<<<2704, 256, 0, stream>>>(x1r, sc1, sh1, x1b);  // lay8 dead
  conv2_mfma<<<dim3(6, 64), 256, 0, stream>>>(x1b, wB2, x2c, bn2sum, bn2sq);
  bn_finalize_kernel<<<1, 64, 0, stream>>>(bn2sum, bn2sq, bn2g, bn2b,
                                           1.f / 36864.f, 64, sc2, sh2);
  bnapply2t_kernel<<<dim3(9, 64), 256, 0, stream>>>(x2c, sc2, sh2, xB);
  fc1_mfma<<<dim3(72, 8), 256, 0, stream>>>(xB, f1w, fc1part);  // x2c dead
  fc1_reduce_kernel<<<128, 256, 0, stream>>>(fc1part, fc1o);
  bn3_kernel<<<8, 64, 0, stream>>>(fc1o, bn3g, bn3b, sc3, sh3);
  fc2_kernel<<<64, 64, 0, stream>>>(fc1o, sc3, sh3, f2w, f2b, (float*)d_out);
}